// Round 1
// baseline (3330.796 us; speedup 1.0000x reference)
//
#include <hip/hip_runtime.h>
#include <hip/hip_bf16.h>
#include <math.h>

// Problem constants (from reference setup_inputs)
//  x:        [N,128] f32      (in 0)
//  edge_index[2,E]   i32      (in 1)
//  edge_x:   [E,16]  f32      (in 2)
//  W1 [16,32] b1[32] W2[32,1] b2[1]   (in 3..6)
//  Wg1[128,128] bg1[128] Wg2[128,40] bg2[40]  (in 7..10)
//  out:      [N,40]  f32

#define NF   128
#define EF   16
#define EFIL 32
#define NFIL 128
#define NCLS 40

// ---------------------------------------------------------------- init deg=1
__global__ __launch_bounds__(256) void init_deg_kernel(float* __restrict__ deg, int N) {
    int i = blockIdx.x * 256 + threadIdx.x;
    if (i < N) deg[i] = 1.0f;   // self-loop weight
}

// ------------------------------------------------- edge MLP + deg scatter-add
__global__ __launch_bounds__(256) void edge_mlp_kernel(
    const float* __restrict__ ex, const float* __restrict__ W1,
    const float* __restrict__ b1, const float* __restrict__ W2,
    const float* __restrict__ b2, const int* __restrict__ col,
    float* __restrict__ ew, float* __restrict__ deg, int E)
{
    __shared__ float sW1[EF * EFIL];
    __shared__ float sb1[EFIL];
    __shared__ float sW2[EFIL];
    __shared__ float sb2;
    int t = threadIdx.x;
    for (int i = t; i < EF * EFIL; i += 256) sW1[i] = W1[i];
    if (t < EFIL) { sb1[t] = b1[t]; sW2[t] = W2[t]; }
    if (t == 0) sb2 = b2[0];
    __syncthreads();

    int e = blockIdx.x * 256 + t;
    if (e >= E) return;

    float xv[EF];
    const float4* exv = (const float4*)(ex) + (size_t)e * (EF / 4);
    #pragma unroll
    for (int q = 0; q < EF / 4; q++) {
        float4 v = exv[q];
        xv[q * 4 + 0] = v.x; xv[q * 4 + 1] = v.y;
        xv[q * 4 + 2] = v.z; xv[q * 4 + 3] = v.w;
    }
    float acc = sb2;
    #pragma unroll
    for (int j = 0; j < EFIL; j++) {
        float h = sb1[j];
        #pragma unroll
        for (int k = 0; k < EF; k++) h += xv[k] * sW1[k * EFIL + j];
        acc += fmaxf(h, 0.0f) * sW2[j];
    }
    float s = 1.0f / (1.0f + expf(-acc));
    ew[e] = s;
    unsafeAtomicAdd(&deg[col[e]], s);
}

// ---------------------------------------------------------------- dinv
__global__ __launch_bounds__(256) void dinv_kernel(float* __restrict__ deg, int N) {
    int i = blockIdx.x * 256 + threadIdx.x;
    if (i < N) {
        float d = deg[i];
        deg[i] = (d > 0.0f) ? rsqrtf(d) : 0.0f;
    }
}

// ------------------------------------------- GEMM1: h1 = x @ Wg1  (128->128)
// 64 rows/block, 256 threads, thread tile = 8 rows x 4 features.
#define G1_ROWS 64
#define XPAD 68   // stride for transposed x tile: 16B-aligned reads, 8-way write conflict only on staging
__global__ __launch_bounds__(256) void gemm1_kernel(
    const float* __restrict__ x, const float* __restrict__ W,
    float* __restrict__ h1, int N)
{
    __shared__ float sW[NF * NF];          // 64 KB
    __shared__ float sx[NF * XPAD];        // ~34.8 KB, sx[k*XPAD + r]
    int t = threadIdx.x;
    for (int i = t; i < NF * NF; i += 256) sW[i] = W[i];
    int row0 = blockIdx.x * G1_ROWS;
    for (int i = t; i < G1_ROWS * NF; i += 256) {
        int r = i >> 7, k = i & 127;
        int gr = row0 + r;
        sx[k * XPAD + r] = (gr < N) ? x[(size_t)gr * NF + k] : 0.0f;
    }
    __syncthreads();

    int fg = t & 31;          // feature group -> f0
    int rg = t >> 5;          // row group    -> r0
    int f0 = fg * 4, r0 = rg * 8;
    float acc[8][4];
    #pragma unroll
    for (int r = 0; r < 8; r++)
        #pragma unroll
        for (int c = 0; c < 4; c++) acc[r][c] = 0.0f;

    #pragma unroll 8
    for (int k = 0; k < NF; k++) {
        float4 w  = *(const float4*)&sW[k * NF + f0];
        float4 xa = *(const float4*)&sx[k * XPAD + r0];
        float4 xb = *(const float4*)&sx[k * XPAD + r0 + 4];
        float xr[8] = {xa.x, xa.y, xa.z, xa.w, xb.x, xb.y, xb.z, xb.w};
        #pragma unroll
        for (int r = 0; r < 8; r++) {
            acc[r][0] += xr[r] * w.x;
            acc[r][1] += xr[r] * w.y;
            acc[r][2] += xr[r] * w.z;
            acc[r][3] += xr[r] * w.w;
        }
    }
    #pragma unroll
    for (int r = 0; r < 8; r++) {
        int gr = row0 + r0 + r;
        if (gr < N) {
            float4 o = {acc[r][0], acc[r][1], acc[r][2], acc[r][3]};
            *(float4*)&h1[(size_t)gr * NF + f0] = o;
        }
    }
}

// ------------------------------- self-loop init: out1 = bg1 + h1 * dinv^2
__global__ __launch_bounds__(256) void selfloop1_kernel(
    const float* __restrict__ h1, const float* __restrict__ dinv,
    const float* __restrict__ bg1, float* __restrict__ out1, int N)
{
    int gid = blockIdx.x * 256 + threadIdx.x;
    if (gid >= N * NF) return;
    int n = gid >> 7, f = gid & 127;
    float di = dinv[n];
    out1[gid] = bg1[f] + h1[gid] * di * di;
}

// ------------------------- conv1 edge scatter: out1[c] += h1[r]*norm, 128-wide
// 32 lanes per edge, float4 per lane. Also stores norm[e] for conv2.
__global__ __launch_bounds__(256) void scatter1_kernel(
    const int* __restrict__ row, const int* __restrict__ col,
    const float* __restrict__ ew, const float* __restrict__ dinv,
    const float* __restrict__ h1, float* __restrict__ out1,
    float* __restrict__ nrm, int E)
{
    int gid = blockIdx.x * 256 + threadIdx.x;
    int e = gid >> 5;
    int l = gid & 31;
    if (e >= E) return;
    int r = row[e], c = col[e];
    float w = dinv[r] * ew[e] * dinv[c];
    if (l == 0) nrm[e] = w;
    float4 v = ((const float4*)(h1 + (size_t)r * NF))[l];
    float* dst = out1 + (size_t)c * NF + l * 4;
    unsafeAtomicAdd(dst + 0, v.x * w);
    unsafeAtomicAdd(dst + 1, v.y * w);
    unsafeAtomicAdd(dst + 2, v.z * w);
    unsafeAtomicAdd(dst + 3, v.w * w);
}

// ----------------------- GEMM2: h2 = relu(out1) @ Wg2  (128 -> 40)
// 64 rows/block, thread tile = 4 rows x 4 features (fg<10 active).
#define G2_ROWS 64
__global__ __launch_bounds__(256) void gemm2_kernel(
    const float* __restrict__ out1, const float* __restrict__ W,
    float* __restrict__ h2, int N)
{
    __shared__ float sW[NF * NCLS];        // 20 KB
    __shared__ float sx[NF * XPAD];        // ~34.8 KB, relu'd, sx[k*XPAD + r]
    int t = threadIdx.x;
    for (int i = t; i < NF * NCLS; i += 256) sW[i] = W[i];
    int row0 = blockIdx.x * G2_ROWS;
    for (int i = t; i < G2_ROWS * NF; i += 256) {
        int r = i >> 7, k = i & 127;
        int gr = row0 + r;
        sx[k * XPAD + r] = (gr < N) ? fmaxf(out1[(size_t)gr * NF + k], 0.0f) : 0.0f;
    }
    __syncthreads();

    int fg = t & 15;           // f0 = fg*4, active if fg < 10
    int rg = t >> 4;           // r0 = rg*4, 16 groups -> 64 rows
    int f0 = fg * 4;
    int f0c = (f0 <= NCLS - 4) ? f0 : (NCLS - 4);  // clamp for idle lanes
    int r0 = rg * 4;
    float acc[4][4];
    #pragma unroll
    for (int r = 0; r < 4; r++)
        #pragma unroll
        for (int c = 0; c < 4; c++) acc[r][c] = 0.0f;

    #pragma unroll 8
    for (int k = 0; k < NF; k++) {
        float4 w  = *(const float4*)&sW[k * NCLS + f0c];
        float4 xa = *(const float4*)&sx[k * XPAD + r0];
        float xr[4] = {xa.x, xa.y, xa.z, xa.w};
        #pragma unroll
        for (int r = 0; r < 4; r++) {
            acc[r][0] += xr[r] * w.x;
            acc[r][1] += xr[r] * w.y;
            acc[r][2] += xr[r] * w.z;
            acc[r][3] += xr[r] * w.w;
        }
    }
    if (f0 <= NCLS - 4) {
        #pragma unroll
        for (int r = 0; r < 4; r++) {
            int gr = row0 + r0 + r;
            if (gr < N) {
                #pragma unroll
                for (int c = 0; c < 4; c++) h2[(size_t)gr * NCLS + f0 + c] = acc[r][c];
            }
        }
    }
}

// ------------------------------- self-loop init: out = bg2 + h2 * dinv^2
__global__ __launch_bounds__(256) void selfloop2_kernel(
    const float* __restrict__ h2, const float* __restrict__ dinv,
    const float* __restrict__ bg2, float* __restrict__ out, int N)
{
    int gid = blockIdx.x * 256 + threadIdx.x;
    if (gid >= N * NCLS) return;
    int n = gid / NCLS, f = gid - n * NCLS;
    float di = dinv[n];
    out[gid] = bg2[f] + h2[gid] * di * di;
}

// ------------------------- conv2 edge scatter: out[c] += h2[r]*norm, 40-wide
__global__ __launch_bounds__(256) void scatter2_kernel(
    const int* __restrict__ row, const int* __restrict__ col,
    const float* __restrict__ nrm, const float* __restrict__ h2,
    float* __restrict__ out, int E)
{
    int gid = blockIdx.x * 256 + threadIdx.x;
    int e = gid / NCLS;
    if (e >= E) return;
    int f = gid - e * NCLS;
    float val = h2[(size_t)row[e] * NCLS + f] * nrm[e];
    unsafeAtomicAdd(&out[(size_t)col[e] * NCLS + f], val);
}

// ============================================================== launch
extern "C" void kernel_launch(void* const* d_in, const int* in_sizes, int n_in,
                              void* d_out, int out_size, void* d_ws, size_t ws_size,
                              hipStream_t stream)
{
    const float* x   = (const float*)d_in[0];
    const int*   ei  = (const int*)d_in[1];
    const float* exf = (const float*)d_in[2];
    const float* W1  = (const float*)d_in[3];
    const float* b1  = (const float*)d_in[4];
    const float* W2  = (const float*)d_in[5];
    const float* b2  = (const float*)d_in[6];
    const float* Wg1 = (const float*)d_in[7];
    const float* bg1 = (const float*)d_in[8];
    const float* Wg2 = (const float*)d_in[9];
    const float* bg2 = (const float*)d_in[10];
    float* out = (float*)d_out;

    int N = in_sizes[0] / NF;
    int E = in_sizes[2] / EF;
    const int* row = ei;
    const int* col = ei + E;

    // workspace layout (floats)
    float* ws   = (float*)d_ws;
    size_t Na   = ((size_t)N + 63) & ~(size_t)63;
    float* deg  = ws;                    // N   (becomes dinv in-place)
    float* ew   = deg  + Na;             // E
    float* nrm  = ew   + E;              // E
    float* h1   = nrm  + E;              // N*128
    float* out1 = h1   + (size_t)N * NF; // N*128
    float* h2   = out1 + (size_t)N * NF; // N*40

    int nb;
    nb = (N + 255) / 256;
    init_deg_kernel<<<nb, 256, 0, stream>>>(deg, N);

    nb = (E + 255) / 256;
    edge_mlp_kernel<<<nb, 256, 0, stream>>>(exf, W1, b1, W2, b2, col, ew, deg, E);

    nb = (N + 255) / 256;
    dinv_kernel<<<nb, 256, 0, stream>>>(deg, N);

    nb = (N + G1_ROWS - 1) / G1_ROWS;
    gemm1_kernel<<<nb, 256, 0, stream>>>(x, Wg1, h1, N);

    nb = (N * NF + 255) / 256;
    selfloop1_kernel<<<nb, 256, 0, stream>>>(h1, deg, bg1, out1, N);

    nb = (int)(((size_t)E * 32 + 255) / 256);
    scatter1_kernel<<<nb, 256, 0, stream>>>(row, col, ew, deg, h1, out1, nrm, E);

    nb = (N + G2_ROWS - 1) / G2_ROWS;
    gemm2_kernel<<<nb, 256, 0, stream>>>(out1, Wg2, h2, N);

    nb = (N * NCLS + 255) / 256;
    selfloop2_kernel<<<nb, 256, 0, stream>>>(h2, deg, bg2, out, N);

    nb = (int)(((size_t)E * NCLS + 255) / 256);
    scatter2_kernel<<<nb, 256, 0, stream>>>(row, col, nrm, h2, out, E);
}

// Round 2
// 877.498 us; speedup vs baseline: 3.7958x; 3.7958x over previous
//
#include <hip/hip_runtime.h>
#include <hip/hip_bf16.h>
#include <math.h>

//  x:        [N,128] f32      (in 0)
//  edge_index[2,E]   i32      (in 1)
//  edge_x:   [E,16]  f32      (in 2)
//  W1 [16,32] b1[32] W2[32,1] b2[1]   (in 3..6)
//  Wg1[128,128] bg1[128] Wg2[128,40] bg2[40]  (in 7..10)
//  out:      [N,40]  f32

#define NF   128
#define EF   16
#define EFIL 32
#define NCLS 40

// ------------------------------------------------ init: deg=1 (self loop), cnt=0
__global__ __launch_bounds__(256) void init_kernel(float* __restrict__ deg,
                                                   int* __restrict__ cnt, int N) {
    int i = blockIdx.x * 256 + threadIdx.x;
    if (i < N) { deg[i] = 1.0f; cnt[i] = 0; }
}

// -------------------------- edge MLP + weighted-degree + histogram (fused)
__global__ __launch_bounds__(256) void edge_mlp_kernel(
    const float* __restrict__ ex, const float* __restrict__ W1,
    const float* __restrict__ b1, const float* __restrict__ W2,
    const float* __restrict__ b2, const int* __restrict__ col,
    float* __restrict__ ew, float* __restrict__ deg,
    int* __restrict__ cnt, int E)
{
    __shared__ float sW1[EF * EFIL];
    __shared__ float sb1[EFIL];
    __shared__ float sW2[EFIL];
    __shared__ float sb2;
    int t = threadIdx.x;
    for (int i = t; i < EF * EFIL; i += 256) sW1[i] = W1[i];
    if (t < EFIL) { sb1[t] = b1[t]; sW2[t] = W2[t]; }
    if (t == 0) sb2 = b2[0];
    __syncthreads();

    int e = blockIdx.x * 256 + t;
    if (e >= E) return;

    float xv[EF];
    const float4* exv = (const float4*)(ex) + (size_t)e * (EF / 4);
    #pragma unroll
    for (int q = 0; q < EF / 4; q++) {
        float4 v = exv[q];
        xv[q * 4 + 0] = v.x; xv[q * 4 + 1] = v.y;
        xv[q * 4 + 2] = v.z; xv[q * 4 + 3] = v.w;
    }
    float acc = sb2;
    #pragma unroll
    for (int j = 0; j < EFIL; j++) {
        float h = sb1[j];
        #pragma unroll
        for (int k = 0; k < EF; k++) h += xv[k] * sW1[k * EFIL + j];
        acc += fmaxf(h, 0.0f) * sW2[j];
    }
    float s = 1.0f / (1.0f + expf(-acc));
    ew[e] = s;
    int c = col[e];
    unsafeAtomicAdd(&deg[c], s);
    atomicAdd(&cnt[c], 1);
}

// ---------------------------------------------------------------- dinv
__global__ __launch_bounds__(256) void dinv_kernel(float* __restrict__ deg, int N) {
    int i = blockIdx.x * 256 + threadIdx.x;
    if (i < N) {
        float d = deg[i];
        deg[i] = (d > 0.0f) ? rsqrtf(d) : 0.0f;
    }
}

// ------------------------------ single-block scan: cnt -> offs (excl), cur copy
__global__ __launch_bounds__(1024) void scan_kernel(
    const int* __restrict__ cnt, int* __restrict__ offs,
    int* __restrict__ cur, int N)
{
    __shared__ int ts[1024];
    int t = threadIdx.x;
    int C = (N + 1023) >> 10;
    int b = t * C;
    int e = b + C; if (e > N) e = N;
    int s = 0;
    for (int i = b; i < e; i++) s += cnt[i];
    ts[t] = s;
    __syncthreads();
    // Hillis-Steele inclusive scan over 1024 thread sums
    for (int d = 1; d < 1024; d <<= 1) {
        int v = (t >= d) ? ts[t - d] : 0;
        __syncthreads();
        ts[t] += v;
        __syncthreads();
    }
    int run = ts[t] - s;  // exclusive prefix for this thread's range
    for (int i = b; i < e; i++) {
        offs[i] = run; cur[i] = run;
        run += cnt[i];
    }
    if (t == 1023) offs[N] = ts[1023];
}

// -------------------------------- bucket edges by destination (counting sort)
__global__ __launch_bounds__(256) void bucket_kernel(
    const int* __restrict__ row, const int* __restrict__ col,
    const float* __restrict__ ew, const float* __restrict__ dinv,
    int* __restrict__ cur, int* __restrict__ src,
    float* __restrict__ wgt, int E)
{
    int e = blockIdx.x * 256 + threadIdx.x;
    if (e >= E) return;
    int r = row[e], c = col[e];
    float w = dinv[r] * ew[e] * dinv[c];
    int p = atomicAdd(&cur[c], 1);
    src[p] = r;
    wgt[p] = w;
}

// ------------------------------------------- GEMM1: h1 = x @ Wg1  (128->128)
#define G1_ROWS 64
#define XPAD 68
__global__ __launch_bounds__(256) void gemm1_kernel(
    const float* __restrict__ x, const float* __restrict__ W,
    float* __restrict__ h1, int N)
{
    __shared__ float sW[NF * NF];
    __shared__ float sx[NF * XPAD];
    int t = threadIdx.x;
    for (int i = t; i < NF * NF; i += 256) sW[i] = W[i];
    int row0 = blockIdx.x * G1_ROWS;
    for (int i = t; i < G1_ROWS * NF; i += 256) {
        int r = i >> 7, k = i & 127;
        int gr = row0 + r;
        sx[k * XPAD + r] = (gr < N) ? x[(size_t)gr * NF + k] : 0.0f;
    }
    __syncthreads();

    int fg = t & 31, rg = t >> 5;
    int f0 = fg * 4, r0 = rg * 8;
    float acc[8][4];
    #pragma unroll
    for (int r = 0; r < 8; r++)
        #pragma unroll
        for (int c = 0; c < 4; c++) acc[r][c] = 0.0f;

    #pragma unroll 8
    for (int k = 0; k < NF; k++) {
        float4 w  = *(const float4*)&sW[k * NF + f0];
        float4 xa = *(const float4*)&sx[k * XPAD + r0];
        float4 xb = *(const float4*)&sx[k * XPAD + r0 + 4];
        float xr[8] = {xa.x, xa.y, xa.z, xa.w, xb.x, xb.y, xb.z, xb.w};
        #pragma unroll
        for (int r = 0; r < 8; r++) {
            acc[r][0] += xr[r] * w.x;
            acc[r][1] += xr[r] * w.y;
            acc[r][2] += xr[r] * w.z;
            acc[r][3] += xr[r] * w.w;
        }
    }
    #pragma unroll
    for (int r = 0; r < 8; r++) {
        int gr = row0 + r0 + r;
        if (gr < N) {
            float4 o = {acc[r][0], acc[r][1], acc[r][2], acc[r][3]};
            *(float4*)&h1[(size_t)gr * NF + f0] = o;
        }
    }
}

// --------------- gather1: out1[c] = bg1 + h1[c]*dinv^2 + sum_e w*h1[src]
// one wave per node; 64 lanes x float2 = 128 features; edges in 64-chunks
__global__ __launch_bounds__(256) void gather1_kernel(
    const int* __restrict__ offs, const int* __restrict__ src,
    const float* __restrict__ wgt, const float* __restrict__ h1,
    const float* __restrict__ dinv, const float* __restrict__ bg1,
    float* __restrict__ out1, int N)
{
    int wid  = threadIdx.x >> 6;
    int lane = threadIdx.x & 63;
    int c = blockIdx.x * 4 + wid;
    if (c >= N) return;
    float di = dinv[c];
    float2 hv = *(const float2*)(h1 + (size_t)c * NF + 2 * lane);
    float2 acc;
    acc.x = bg1[2 * lane]     + hv.x * di * di;
    acc.y = bg1[2 * lane + 1] + hv.y * di * di;

    int beg = offs[c], end = offs[c + 1];
    for (int e0 = beg; e0 < end; e0 += 64) {
        int idx = e0 + lane;
        int   sv = 0; float wv = 0.0f;
        if (idx < end) { sv = src[idx]; wv = wgt[idx]; }
        int m = end - e0; if (m > 64) m = 64;
        for (int j = 0; j < m; j++) {
            int   s = __shfl(sv, j);
            float w = __shfl(wv, j);
            float2 v = *(const float2*)(h1 + (size_t)s * NF + 2 * lane);
            acc.x += w * v.x;
            acc.y += w * v.y;
        }
    }
    *(float2*)(out1 + (size_t)c * NF + 2 * lane) = acc;
}

// ----------------------- GEMM2: h2 = relu(out1) @ Wg2  (128 -> 40)
#define G2_ROWS 64
__global__ __launch_bounds__(256) void gemm2_kernel(
    const float* __restrict__ out1, const float* __restrict__ W,
    float* __restrict__ h2, int N)
{
    __shared__ float sW[NF * NCLS];
    __shared__ float sx[NF * XPAD];
    int t = threadIdx.x;
    for (int i = t; i < NF * NCLS; i += 256) sW[i] = W[i];
    int row0 = blockIdx.x * G2_ROWS;
    for (int i = t; i < G2_ROWS * NF; i += 256) {
        int r = i >> 7, k = i & 127;
        int gr = row0 + r;
        sx[k * XPAD + r] = (gr < N) ? fmaxf(out1[(size_t)gr * NF + k], 0.0f) : 0.0f;
    }
    __syncthreads();

    int fg = t & 15, rg = t >> 4;
    int f0 = fg * 4;
    int f0c = (f0 <= NCLS - 4) ? f0 : (NCLS - 4);
    int r0 = rg * 4;
    float acc[4][4];
    #pragma unroll
    for (int r = 0; r < 4; r++)
        #pragma unroll
        for (int c = 0; c < 4; c++) acc[r][c] = 0.0f;

    #pragma unroll 8
    for (int k = 0; k < NF; k++) {
        float4 w  = *(const float4*)&sW[k * NCLS + f0c];
        float4 xa = *(const float4*)&sx[k * XPAD + r0];
        float xr[4] = {xa.x, xa.y, xa.z, xa.w};
        #pragma unroll
        for (int r = 0; r < 4; r++) {
            acc[r][0] += xr[r] * w.x;
            acc[r][1] += xr[r] * w.y;
            acc[r][2] += xr[r] * w.z;
            acc[r][3] += xr[r] * w.w;
        }
    }
    if (f0 <= NCLS - 4) {
        #pragma unroll
        for (int r = 0; r < 4; r++) {
            int gr = row0 + r0 + r;
            if (gr < N) {
                #pragma unroll
                for (int c = 0; c < 4; c++) h2[(size_t)gr * NCLS + f0 + c] = acc[r][c];
            }
        }
    }
}

// --------------- gather2: out[c] = bg2 + h2[c]*dinv^2 + sum_e w*h2[src]
// one wave per node; lanes 0..39 hold features; all lanes stage edge chunks
__global__ __launch_bounds__(256) void gather2_kernel(
    const int* __restrict__ offs, const int* __restrict__ src,
    const float* __restrict__ wgt, const float* __restrict__ h2,
    const float* __restrict__ dinv, const float* __restrict__ bg2,
    float* __restrict__ out, int N)
{
    int wid  = threadIdx.x >> 6;
    int lane = threadIdx.x & 63;
    int c = blockIdx.x * 4 + wid;
    if (c >= N) return;
    float di = dinv[c];
    float acc = 0.0f;
    if (lane < NCLS) acc = bg2[lane] + h2[(size_t)c * NCLS + lane] * di * di;

    int beg = offs[c], end = offs[c + 1];
    for (int e0 = beg; e0 < end; e0 += 64) {
        int idx = e0 + lane;
        int   sv = 0; float wv = 0.0f;
        if (idx < end) { sv = src[idx]; wv = wgt[idx]; }
        int m = end - e0; if (m > 64) m = 64;
        for (int j = 0; j < m; j++) {
            int   s = __shfl(sv, j);
            float w = __shfl(wv, j);
            if (lane < NCLS) acc += w * h2[(size_t)s * NCLS + lane];
        }
    }
    if (lane < NCLS) out[(size_t)c * NCLS + lane] = acc;
}

// ============================================================== launch
extern "C" void kernel_launch(void* const* d_in, const int* in_sizes, int n_in,
                              void* d_out, int out_size, void* d_ws, size_t ws_size,
                              hipStream_t stream)
{
    const float* x   = (const float*)d_in[0];
    const int*   ei  = (const int*)d_in[1];
    const float* exf = (const float*)d_in[2];
    const float* W1  = (const float*)d_in[3];
    const float* b1  = (const float*)d_in[4];
    const float* W2  = (const float*)d_in[5];
    const float* b2  = (const float*)d_in[6];
    const float* Wg1 = (const float*)d_in[7];
    const float* bg1 = (const float*)d_in[8];
    const float* Wg2 = (const float*)d_in[9];
    const float* bg2 = (const float*)d_in[10];
    float* out = (float*)d_out;

    int N = in_sizes[0] / NF;
    int E = in_sizes[2] / EF;
    const int* row = ei;
    const int* col = ei + E;

    // workspace bump allocator (4-byte words, 16B-aligned regions)
    char* base = (char*)d_ws;
    size_t off = 0;
    auto alloc = [&](size_t words) -> void* {
        void* p = base + off * 4;
        off += (words + 3) & ~(size_t)3;
        return p;
    };
    float* deg  = (float*)alloc(N);          // becomes dinv in-place
    int*   cnt  = (int*)  alloc(N);
    int*   offs = (int*)  alloc(N + 1);
    int*   cur  = (int*)  alloc(N);
    float* ew   = (float*)alloc(E);
    int*   srcb = (int*)  alloc(E);
    float* wgt  = (float*)alloc(E);
    float* h1   = (float*)alloc((size_t)N * NF);
    float* out1 = (float*)alloc((size_t)N * NF);
    float* h2   = h1;  // h1 dead after gather1; reuse for h2 [N*40]

    int nb;
    nb = (N + 255) / 256;
    init_kernel<<<nb, 256, 0, stream>>>(deg, cnt, N);

    nb = (E + 255) / 256;
    edge_mlp_kernel<<<nb, 256, 0, stream>>>(exf, W1, b1, W2, b2, col, ew, deg, cnt, E);

    nb = (N + 255) / 256;
    dinv_kernel<<<nb, 256, 0, stream>>>(deg, N);

    scan_kernel<<<1, 1024, 0, stream>>>(cnt, offs, cur, N);

    nb = (E + 255) / 256;
    bucket_kernel<<<nb, 256, 0, stream>>>(row, col, ew, deg, cur, srcb, wgt, E);

    nb = (N + G1_ROWS - 1) / G1_ROWS;
    gemm1_kernel<<<nb, 256, 0, stream>>>(x, Wg1, h1, N);

    nb = (N + 3) / 4;
    gather1_kernel<<<nb, 256, 0, stream>>>(offs, srcb, wgt, h1, deg, bg1, out1, N);

    nb = (N + G2_ROWS - 1) / G2_ROWS;
    gemm2_kernel<<<nb, 256, 0, stream>>>(out1, Wg2, h2, N);

    nb = (N + 3) / 4;
    gather2_kernel<<<nb, 256, 0, stream>>>(offs, srcb, wgt, h2, deg, bg2, out, N);
}

// Round 3
// 804.586 us; speedup vs baseline: 4.1398x; 1.0906x over previous
//
#include <hip/hip_runtime.h>
#include <hip/hip_bf16.h>
#include <math.h>

//  x:        [N,128] f32      (in 0)
//  edge_index[2,E]   i32      (in 1)
//  edge_x:   [E,16]  f32      (in 2)
//  W1 [16,32] b1[32] W2[32,1] b2[1]   (in 3..6)
//  Wg1[128,128] bg1[128] Wg2[128,40] bg2[40]  (in 7..10)
//  out:      [N,40]  f32

#define NF   128
#define EF   16
#define EFIL 32
#define NCLS 40
#define TILE 4096   // edges per tile for pass-1 sort

// -------------------------- edge MLP (pure compute, no atomics)
__global__ __launch_bounds__(256) void edge_mlp_kernel(
    const float* __restrict__ ex, const float* __restrict__ W1,
    const float* __restrict__ b1, const float* __restrict__ W2,
    const float* __restrict__ b2, float* __restrict__ ew, int E)
{
    __shared__ float sW1[EF * EFIL];
    __shared__ float sb1[EFIL];
    __shared__ float sW2[EFIL];
    __shared__ float sb2;
    int t = threadIdx.x;
    for (int i = t; i < EF * EFIL; i += 256) sW1[i] = W1[i];
    if (t < EFIL) { sb1[t] = b1[t]; sW2[t] = W2[t]; }
    if (t == 0) sb2 = b2[0];
    __syncthreads();

    int e = blockIdx.x * 256 + t;
    if (e >= E) return;

    float xv[EF];
    const float4* exv = (const float4*)(ex) + (size_t)e * (EF / 4);
    #pragma unroll
    for (int q = 0; q < EF / 4; q++) {
        float4 v = exv[q];
        xv[q * 4 + 0] = v.x; xv[q * 4 + 1] = v.y;
        xv[q * 4 + 2] = v.z; xv[q * 4 + 3] = v.w;
    }
    float acc = sb2;
    #pragma unroll
    for (int j = 0; j < EFIL; j++) {
        float h = sb1[j];
        #pragma unroll
        for (int k = 0; k < EF; k++) h += xv[k] * sW1[k * EFIL + j];
        acc += fmaxf(h, 0.0f) * sW2[j];
    }
    ew[e] = 1.0f / (1.0f + expf(-acc));
}

// -------------------- pass1 histogram: digit = col>>8, LDS only
__global__ __launch_bounds__(256) void hist1_kernel(
    const int* __restrict__ col, int* __restrict__ hist, int E, int ntiles)
{
    __shared__ int h[256];
    int t = threadIdx.x;
    h[t] = 0;
    __syncthreads();
    int tile = blockIdx.x;
    int base = tile * TILE;
    int end = base + TILE; if (end > E) end = E;
    for (int i = base + t; i < end; i += 256)
        atomicAdd(&h[col[i] >> 8], 1);
    __syncthreads();
    hist[t * ntiles + tile] = h[t];
}

// -------------------- exclusive scan of hist (length L) -> hscan
__global__ __launch_bounds__(1024) void scan_kernel(
    const int* __restrict__ hist, int* __restrict__ hscan, int L)
{
    __shared__ int ts[1024];
    int t = threadIdx.x;
    int C = (L + 1023) >> 10;
    int b = t * C;
    int e = b + C; if (e > L) e = L;
    int s = 0;
    for (int i = b; i < e; i++) s += hist[i];
    ts[t] = s;
    __syncthreads();
    for (int d = 1; d < 1024; d <<= 1) {
        int v = (t >= d) ? ts[t - d] : 0;
        __syncthreads();
        ts[t] += v;
        __syncthreads();
    }
    int run = ts[t] - s;
    for (int i = b; i < e; i++) {
        hscan[i] = run;
        run += hist[i];
    }
}

// -------------------- pass1 scatter: bucket by col>>8 (unstable, LDS cursors)
__global__ __launch_bounds__(256) void scatter1_kernel(
    const int* __restrict__ row, const int* __restrict__ col,
    const float* __restrict__ ew, const int* __restrict__ hscan,
    int* __restrict__ keyS, int* __restrict__ srcS, float* __restrict__ ewS,
    int E, int ntiles)
{
    __shared__ int cur[256];
    int t = threadIdx.x;
    int tile = blockIdx.x;
    cur[t] = hscan[t * ntiles + tile];
    __syncthreads();
    int base = tile * TILE;
    int end = base + TILE; if (end > E) end = E;
    for (int i = base + t; i < end; i += 256) {
        int c = col[i];
        int p = atomicAdd(&cur[c >> 8], 1);
        keyS[p] = c;
        srcS[p] = row[i];
        ewS[p] = ew[i];
    }
}

// ---- pass2: per-bucket counting sort by col&255 + offs + deg/dinv (fused)
__global__ __launch_bounds__(512) void bucket_sort_kernel(
    const int* __restrict__ keyS, const int* __restrict__ srcS,
    const float* __restrict__ ewS, const int* __restrict__ hscan,
    int* __restrict__ srcF, float* __restrict__ wgtF,
    int* __restrict__ offs, float* __restrict__ dinv,
    int E, int ntiles, int N)
{
    __shared__ int   cnt[256];
    __shared__ int   scan[256];
    __shared__ int   cursor[256];
    __shared__ float dsum[256];
    __shared__ float sdinv[256];
    int t = threadIdx.x;
    int b = blockIdx.x;
    if (t == 0 && b == 0) offs[N] = E;
    int bstart = hscan[b * ntiles];
    int bend = (b == 255) ? E : hscan[(b + 1) * ntiles];
    if (t < 256) { cnt[t] = 0; dsum[t] = 0.0f; sdinv[t] = 0.0f; }
    __syncthreads();
    for (int i = bstart + t; i < bend; i += 512) {
        int lo = keyS[i] & 255;
        atomicAdd(&cnt[lo], 1);
        atomicAdd(&dsum[lo], ewS[i]);
    }
    __syncthreads();
    if (t < 256) scan[t] = cnt[t];
    __syncthreads();
    for (int d = 1; d < 256; d <<= 1) {
        int v = 0;
        if (t < 256 && t >= d) v = scan[t - d];
        __syncthreads();
        if (t < 256) scan[t] += v;
        __syncthreads();
    }
    if (t < 256) {
        int excl = scan[t] - cnt[t];
        int c = (b << 8) + t;
        cursor[t] = bstart + excl;
        if (c < N) {
            offs[c] = bstart + excl;
            float deg = 1.0f + dsum[t];
            float di = rsqrtf(deg);
            sdinv[t] = di;
            dinv[c] = di;
        }
    }
    __syncthreads();
    for (int i = bstart + t; i < bend; i += 512) {
        int k = keyS[i];
        int lo = k & 255;
        int p = atomicAdd(&cursor[lo], 1);
        srcF[p] = srcS[i];
        wgtF[p] = ewS[i] * sdinv[lo];   // * dinv[col]; dinv[src] applied later
    }
}

// -------------------- normalize: wgt *= dinv[src]
__global__ __launch_bounds__(256) void normalize_kernel(
    int* __restrict__ srcF, float* __restrict__ wgtF,
    const float* __restrict__ dinv, int E)
{
    int p = blockIdx.x * 256 + threadIdx.x;
    if (p < E) wgtF[p] *= dinv[srcF[p]];
}

// ------------------------------------------- GEMM1: h1 = x @ Wg1  (128->128)
#define G1_ROWS 64
#define XPAD 68
__global__ __launch_bounds__(256) void gemm1_kernel(
    const float* __restrict__ x, const float* __restrict__ W,
    float* __restrict__ h1, int N)
{
    __shared__ float sW[NF * NF];
    __shared__ float sx[NF * XPAD];
    int t = threadIdx.x;
    for (int i = t; i < NF * NF; i += 256) sW[i] = W[i];
    int row0 = blockIdx.x * G1_ROWS;
    for (int i = t; i < G1_ROWS * NF; i += 256) {
        int r = i >> 7, k = i & 127;
        int gr = row0 + r;
        sx[k * XPAD + r] = (gr < N) ? x[(size_t)gr * NF + k] : 0.0f;
    }
    __syncthreads();

    int fg = t & 31, rg = t >> 5;
    int f0 = fg * 4, r0 = rg * 8;
    float acc[8][4];
    #pragma unroll
    for (int r = 0; r < 8; r++)
        #pragma unroll
        for (int c = 0; c < 4; c++) acc[r][c] = 0.0f;

    #pragma unroll 8
    for (int k = 0; k < NF; k++) {
        float4 w  = *(const float4*)&sW[k * NF + f0];
        float4 xa = *(const float4*)&sx[k * XPAD + r0];
        float4 xb = *(const float4*)&sx[k * XPAD + r0 + 4];
        float xr[8] = {xa.x, xa.y, xa.z, xa.w, xb.x, xb.y, xb.z, xb.w};
        #pragma unroll
        for (int r = 0; r < 8; r++) {
            acc[r][0] += xr[r] * w.x;
            acc[r][1] += xr[r] * w.y;
            acc[r][2] += xr[r] * w.z;
            acc[r][3] += xr[r] * w.w;
        }
    }
    #pragma unroll
    for (int r = 0; r < 8; r++) {
        int gr = row0 + r0 + r;
        if (gr < N) {
            float4 o = {acc[r][0], acc[r][1], acc[r][2], acc[r][3]};
            *(float4*)&h1[(size_t)gr * NF + f0] = o;
        }
    }
}

// --------------- gather1: out1[c] = bg1 + h1[c]*dinv^2 + sum_e w*h1[src]
__global__ __launch_bounds__(256) void gather1_kernel(
    const int* __restrict__ offs, const int* __restrict__ src,
    const float* __restrict__ wgt, const float* __restrict__ h1,
    const float* __restrict__ dinv, const float* __restrict__ bg1,
    float* __restrict__ out1, int N)
{
    int wid  = threadIdx.x >> 6;
    int lane = threadIdx.x & 63;
    int c = blockIdx.x * 4 + wid;
    if (c >= N) return;
    float di = dinv[c];
    float2 hv = *(const float2*)(h1 + (size_t)c * NF + 2 * lane);
    float2 acc;
    acc.x = bg1[2 * lane]     + hv.x * di * di;
    acc.y = bg1[2 * lane + 1] + hv.y * di * di;

    int beg = offs[c], end = offs[c + 1];
    for (int e0 = beg; e0 < end; e0 += 64) {
        int idx = e0 + lane;
        int   sv = 0; float wv = 0.0f;
        if (idx < end) { sv = src[idx]; wv = wgt[idx]; }
        int m = end - e0; if (m > 64) m = 64;
        for (int j = 0; j < m; j++) {
            int   s = __shfl(sv, j);
            float w = __shfl(wv, j);
            float2 v = *(const float2*)(h1 + (size_t)s * NF + 2 * lane);
            acc.x += w * v.x;
            acc.y += w * v.y;
        }
    }
    *(float2*)(out1 + (size_t)c * NF + 2 * lane) = acc;
}

// ----------------------- GEMM2: h2 = relu(out1) @ Wg2  (128 -> 40)
#define G2_ROWS 64
__global__ __launch_bounds__(256) void gemm2_kernel(
    const float* __restrict__ out1, const float* __restrict__ W,
    float* __restrict__ h2, int N)
{
    __shared__ float sW[NF * NCLS];
    __shared__ float sx[NF * XPAD];
    int t = threadIdx.x;
    for (int i = t; i < NF * NCLS; i += 256) sW[i] = W[i];
    int row0 = blockIdx.x * G2_ROWS;
    for (int i = t; i < G2_ROWS * NF; i += 256) {
        int r = i >> 7, k = i & 127;
        int gr = row0 + r;
        sx[k * XPAD + r] = (gr < N) ? fmaxf(out1[(size_t)gr * NF + k], 0.0f) : 0.0f;
    }
    __syncthreads();

    int fg = t & 15, rg = t >> 4;
    int f0 = fg * 4;
    int f0c = (f0 <= NCLS - 4) ? f0 : (NCLS - 4);
    int r0 = rg * 4;
    float acc[4][4];
    #pragma unroll
    for (int r = 0; r < 4; r++)
        #pragma unroll
        for (int c = 0; c < 4; c++) acc[r][c] = 0.0f;

    #pragma unroll 8
    for (int k = 0; k < NF; k++) {
        float4 w  = *(const float4*)&sW[k * NCLS + f0c];
        float4 xa = *(const float4*)&sx[k * XPAD + r0];
        float xr[4] = {xa.x, xa.y, xa.z, xa.w};
        #pragma unroll
        for (int r = 0; r < 4; r++) {
            acc[r][0] += xr[r] * w.x;
            acc[r][1] += xr[r] * w.y;
            acc[r][2] += xr[r] * w.z;
            acc[r][3] += xr[r] * w.w;
        }
    }
    if (f0 <= NCLS - 4) {
        #pragma unroll
        for (int r = 0; r < 4; r++) {
            int gr = row0 + r0 + r;
            if (gr < N) {
                #pragma unroll
                for (int c = 0; c < 4; c++) h2[(size_t)gr * NCLS + f0 + c] = acc[r][c];
            }
        }
    }
}

// --------------- gather2: out[c] = bg2 + h2[c]*dinv^2 + sum_e w*h2[src]
__global__ __launch_bounds__(256) void gather2_kernel(
    const int* __restrict__ offs, const int* __restrict__ src,
    const float* __restrict__ wgt, const float* __restrict__ h2,
    const float* __restrict__ dinv, const float* __restrict__ bg2,
    float* __restrict__ out, int N)
{
    int wid  = threadIdx.x >> 6;
    int lane = threadIdx.x & 63;
    int c = blockIdx.x * 4 + wid;
    if (c >= N) return;
    float di = dinv[c];
    float acc = 0.0f;
    if (lane < NCLS) acc = bg2[lane] + h2[(size_t)c * NCLS + lane] * di * di;

    int beg = offs[c], end = offs[c + 1];
    for (int e0 = beg; e0 < end; e0 += 64) {
        int idx = e0 + lane;
        int   sv = 0; float wv = 0.0f;
        if (idx < end) { sv = src[idx]; wv = wgt[idx]; }
        int m = end - e0; if (m > 64) m = 64;
        for (int j = 0; j < m; j++) {
            int   s = __shfl(sv, j);
            float w = __shfl(wv, j);
            if (lane < NCLS) acc += w * h2[(size_t)s * NCLS + lane];
        }
    }
    if (lane < NCLS) out[(size_t)c * NCLS + lane] = acc;
}

// ============================================================== launch
extern "C" void kernel_launch(void* const* d_in, const int* in_sizes, int n_in,
                              void* d_out, int out_size, void* d_ws, size_t ws_size,
                              hipStream_t stream)
{
    const float* x   = (const float*)d_in[0];
    const int*   ei  = (const int*)d_in[1];
    const float* exf = (const float*)d_in[2];
    const float* W1  = (const float*)d_in[3];
    const float* b1  = (const float*)d_in[4];
    const float* W2  = (const float*)d_in[5];
    const float* b2  = (const float*)d_in[6];
    const float* Wg1 = (const float*)d_in[7];
    const float* bg1 = (const float*)d_in[8];
    const float* Wg2 = (const float*)d_in[9];
    const float* bg2 = (const float*)d_in[10];
    float* out = (float*)d_out;

    int N = in_sizes[0] / NF;
    int E = in_sizes[2] / EF;
    const int* row = ei;
    const int* col = ei + E;
    int ntiles = (E + TILE - 1) / TILE;
    int L = 256 * ntiles;

    // workspace bump allocator (4-byte words)
    char* base = (char*)d_ws;
    size_t off = 0;
    auto alloc = [&](size_t words) -> void* {
        void* p = base + off * 4;
        off += (words + 3) & ~(size_t)3;
        return p;
    };
    // region A: ew + pass1 output (4E words) -- later reused as h1 / h2
    size_t awords = (size_t)4 * E;
    size_t h1words = (size_t)N * NF;
    if (h1words > awords) awords = h1words;
    float* regA = (float*)alloc(awords);
    float* ew   = regA;
    int*   keyS = (int*)(regA + E);
    int*   srcS = (int*)(regA + 2 * (size_t)E);
    float* ewS  = regA + 3 * (size_t)E;
    float* h1   = regA;                      // alias (after sort consumed)
    float* h2   = regA;                      // alias (after gather1 consumed)
    // region B: final CSR
    int*   srcF = (int*)  alloc(E);
    float* wgtF = (float*)alloc(E);
    // region C: out1
    float* out1 = (float*)alloc((size_t)N * NF);
    // region D: small
    float* dinv = (float*)alloc(N);
    int*   offs = (int*)  alloc(N + 1);
    int*   hist = (int*)  alloc(L);
    int*   hscn = (int*)  alloc(L);

    int nb;
    nb = (E + 255) / 256;
    edge_mlp_kernel<<<nb, 256, 0, stream>>>(exf, W1, b1, W2, b2, ew, E);

    hist1_kernel<<<ntiles, 256, 0, stream>>>(col, hist, E, ntiles);
    scan_kernel<<<1, 1024, 0, stream>>>(hist, hscn, L);
    scatter1_kernel<<<ntiles, 256, 0, stream>>>(row, col, ew, hscn,
                                                keyS, srcS, ewS, E, ntiles);
    bucket_sort_kernel<<<256, 512, 0, stream>>>(keyS, srcS, ewS, hscn,
                                                srcF, wgtF, offs, dinv,
                                                E, ntiles, N);
    nb = (E + 255) / 256;
    normalize_kernel<<<nb, 256, 0, stream>>>(srcF, wgtF, dinv, E);

    nb = (N + G1_ROWS - 1) / G1_ROWS;
    gemm1_kernel<<<nb, 256, 0, stream>>>(x, Wg1, h1, N);

    nb = (N + 3) / 4;
    gather1_kernel<<<nb, 256, 0, stream>>>(offs, srcF, wgtF, h1, dinv, bg1, out1, N);

    nb = (N + G2_ROWS - 1) / G2_ROWS;
    gemm2_kernel<<<nb, 256, 0, stream>>>(out1, Wg2, h2, N);

    nb = (N + 3) / 4;
    gather2_kernel<<<nb, 256, 0, stream>>>(offs, srcF, wgtF, h2, dinv, bg2, out, N);
}

// Round 4
// 652.901 us; speedup vs baseline: 5.1015x; 1.2323x over previous
//
#include <hip/hip_runtime.h>
#include <hip/hip_bf16.h>
#include <math.h>

//  x:        [N,128] f32      (in 0)
//  edge_index[2,E]   i32      (in 1)
//  edge_x:   [E,16]  f32      (in 2)
//  W1 [16,32] b1[32] W2[32,1] b2[1]   (in 3..6)
//  Wg1[128,128] bg1[128] Wg2[128,40] bg2[40]  (in 7..10)
//  out:      [N,40]  f32

#define NF   128
#define EF   16
#define EFIL 32
#define NCLS 40
#define TILE 4096   // edges per tile for pass-1 sort

// -------------------------- edge MLP (pure compute, no atomics)
__global__ __launch_bounds__(256) void edge_mlp_kernel(
    const float* __restrict__ ex, const float* __restrict__ W1,
    const float* __restrict__ b1, const float* __restrict__ W2,
    const float* __restrict__ b2, float* __restrict__ ew, int E)
{
    __shared__ float sW1[EF * EFIL];
    __shared__ float sb1[EFIL];
    __shared__ float sW2[EFIL];
    __shared__ float sb2;
    int t = threadIdx.x;
    for (int i = t; i < EF * EFIL; i += 256) sW1[i] = W1[i];
    if (t < EFIL) { sb1[t] = b1[t]; sW2[t] = W2[t]; }
    if (t == 0) sb2 = b2[0];
    __syncthreads();

    int e = blockIdx.x * 256 + t;
    if (e >= E) return;

    float xv[EF];
    const float4* exv = (const float4*)(ex) + (size_t)e * (EF / 4);
    #pragma unroll
    for (int q = 0; q < EF / 4; q++) {
        float4 v = exv[q];
        xv[q * 4 + 0] = v.x; xv[q * 4 + 1] = v.y;
        xv[q * 4 + 2] = v.z; xv[q * 4 + 3] = v.w;
    }
    float acc = sb2;
    #pragma unroll
    for (int j = 0; j < EFIL; j++) {
        float h = sb1[j];
        #pragma unroll
        for (int k = 0; k < EF; k++) h += xv[k] * sW1[k * EFIL + j];
        acc += fmaxf(h, 0.0f) * sW2[j];
    }
    ew[e] = 1.0f / (1.0f + expf(-acc));
}

// -------------------- pass1 histogram: digit = col>>8, LDS only
__global__ __launch_bounds__(256) void hist1_kernel(
    const int* __restrict__ col, int* __restrict__ hist, int E, int ntiles)
{
    __shared__ int h[256];
    int t = threadIdx.x;
    h[t] = 0;
    __syncthreads();
    int tile = blockIdx.x;
    int base = tile * TILE;
    int end = base + TILE; if (end > E) end = E;
    for (int i = base + t; i < end; i += 256)
        atomicAdd(&h[col[i] >> 8], 1);
    __syncthreads();
    hist[t * ntiles + tile] = h[t];
}

// ---- scanA: one block per digit; exclusive scan of hist[d][0..ntiles) in
//      place (digit-major, coalesced), digit total -> dtot[d]
__global__ __launch_bounds__(256) void scanA_kernel(
    int* __restrict__ hist, int* __restrict__ dtot, int ntiles)
{
    __shared__ int ts[256];
    int d = blockIdx.x;
    int t = threadIdx.x;
    int* hrow = hist + (size_t)d * ntiles;
    int C = (ntiles + 255) >> 8;
    int b = t * C;
    int e = b + C; if (e > ntiles) e = ntiles;
    int s = 0;
    for (int i = b; i < e; i++) s += hrow[i];
    ts[t] = s;
    __syncthreads();
    for (int dd = 1; dd < 256; dd <<= 1) {
        int v = (t >= dd) ? ts[t - dd] : 0;
        __syncthreads();
        ts[t] += v;
        __syncthreads();
    }
    int run = ts[t] - s;   // exclusive prefix of this thread's chunk
    for (int i = b; i < e; i++) {
        int v = hrow[i];
        hrow[i] = run;     // in-place exclusive within-digit prefix
        run += v;
    }
    if (t == 255) dtot[d] = ts[255];
}

// ---- scanB: exclusive scan of 256 digit totals -> dbase[0..256]
__global__ __launch_bounds__(256) void scanB_kernel(
    const int* __restrict__ dtot, int* __restrict__ dbase, int E)
{
    __shared__ int ts[256];
    int t = threadIdx.x;
    int s = dtot[t];
    ts[t] = s;
    __syncthreads();
    for (int dd = 1; dd < 256; dd <<= 1) {
        int v = (t >= dd) ? ts[t - dd] : 0;
        __syncthreads();
        ts[t] += v;
        __syncthreads();
    }
    dbase[t] = ts[t] - s;
    if (t == 255) dbase[256] = E;
}

// -------------------- pass1 scatter: bucket by col>>8 (unstable, LDS cursors)
__global__ __launch_bounds__(256) void scatter1_kernel(
    const int* __restrict__ row, const int* __restrict__ col,
    const float* __restrict__ ew, const int* __restrict__ hscan,
    const int* __restrict__ dbase,
    int* __restrict__ keyS, int* __restrict__ srcS, float* __restrict__ ewS,
    int E, int ntiles)
{
    __shared__ int cur[256];
    int t = threadIdx.x;
    int tile = blockIdx.x;
    cur[t] = dbase[t] + hscan[t * ntiles + tile];
    __syncthreads();
    int base = tile * TILE;
    int end = base + TILE; if (end > E) end = E;
    for (int i = base + t; i < end; i += 256) {
        int c = col[i];
        int p = atomicAdd(&cur[c >> 8], 1);
        keyS[p] = c;
        srcS[p] = row[i];
        ewS[p] = ew[i];
    }
}

// ---- pass2: per-bucket counting sort by col&255 + offs + deg/dinv (fused)
__global__ __launch_bounds__(512) void bucket_sort_kernel(
    const int* __restrict__ keyS, const int* __restrict__ srcS,
    const float* __restrict__ ewS, const int* __restrict__ dbase,
    int* __restrict__ srcF, float* __restrict__ wgtF,
    int* __restrict__ offs, float* __restrict__ dinv,
    int E, int N)
{
    __shared__ int   cnt[256];
    __shared__ int   scan[256];
    __shared__ int   cursor[256];
    __shared__ float dsum[256];
    __shared__ float sdinv[256];
    int t = threadIdx.x;
    int b = blockIdx.x;
    if (t == 0 && b == 0) offs[N] = E;
    int bstart = dbase[b];
    int bend   = dbase[b + 1];
    if (t < 256) { cnt[t] = 0; dsum[t] = 0.0f; sdinv[t] = 0.0f; }
    __syncthreads();
    for (int i = bstart + t; i < bend; i += 512) {
        int lo = keyS[i] & 255;
        atomicAdd(&cnt[lo], 1);
        atomicAdd(&dsum[lo], ewS[i]);
    }
    __syncthreads();
    if (t < 256) scan[t] = cnt[t];
    __syncthreads();
    for (int d = 1; d < 256; d <<= 1) {
        int v = 0;
        if (t < 256 && t >= d) v = scan[t - d];
        __syncthreads();
        if (t < 256) scan[t] += v;
        __syncthreads();
    }
    if (t < 256) {
        int excl = scan[t] - cnt[t];
        int c = (b << 8) + t;
        cursor[t] = bstart + excl;
        if (c < N) {
            offs[c] = bstart + excl;
            float deg = 1.0f + dsum[t];
            float di = rsqrtf(deg);
            sdinv[t] = di;
            dinv[c] = di;
        }
    }
    __syncthreads();
    for (int i = bstart + t; i < bend; i += 512) {
        int k = keyS[i];
        int lo = k & 255;
        int p = atomicAdd(&cursor[lo], 1);
        srcF[p] = srcS[i];
        wgtF[p] = ewS[i] * sdinv[lo];   // * dinv[col]; dinv[src] applied later
    }
}

// -------------------- normalize: wgt *= dinv[src]
__global__ __launch_bounds__(256) void normalize_kernel(
    int* __restrict__ srcF, float* __restrict__ wgtF,
    const float* __restrict__ dinv, int E)
{
    int p = blockIdx.x * 256 + threadIdx.x;
    if (p < E) wgtF[p] *= dinv[srcF[p]];
}

// ------------------------------------------- GEMM1: h1 = x @ Wg1  (128->128)
#define G1_ROWS 64
#define XPAD 68
__global__ __launch_bounds__(256) void gemm1_kernel(
    const float* __restrict__ x, const float* __restrict__ W,
    float* __restrict__ h1, int N)
{
    __shared__ float sW[NF * NF];
    __shared__ float sx[NF * XPAD];
    int t = threadIdx.x;
    for (int i = t; i < NF * NF; i += 256) sW[i] = W[i];
    int row0 = blockIdx.x * G1_ROWS;
    for (int i = t; i < G1_ROWS * NF; i += 256) {
        int r = i >> 7, k = i & 127;
        int gr = row0 + r;
        sx[k * XPAD + r] = (gr < N) ? x[(size_t)gr * NF + k] : 0.0f;
    }
    __syncthreads();

    int fg = t & 31, rg = t >> 5;
    int f0 = fg * 4, r0 = rg * 8;
    float acc[8][4];
    #pragma unroll
    for (int r = 0; r < 8; r++)
        #pragma unroll
        for (int c = 0; c < 4; c++) acc[r][c] = 0.0f;

    #pragma unroll 8
    for (int k = 0; k < NF; k++) {
        float4 w  = *(const float4*)&sW[k * NF + f0];
        float4 xa = *(const float4*)&sx[k * XPAD + r0];
        float4 xb = *(const float4*)&sx[k * XPAD + r0 + 4];
        float xr[8] = {xa.x, xa.y, xa.z, xa.w, xb.x, xb.y, xb.z, xb.w};
        #pragma unroll
        for (int r = 0; r < 8; r++) {
            acc[r][0] += xr[r] * w.x;
            acc[r][1] += xr[r] * w.y;
            acc[r][2] += xr[r] * w.z;
            acc[r][3] += xr[r] * w.w;
        }
    }
    #pragma unroll
    for (int r = 0; r < 8; r++) {
        int gr = row0 + r0 + r;
        if (gr < N) {
            float4 o = {acc[r][0], acc[r][1], acc[r][2], acc[r][3]};
            *(float4*)&h1[(size_t)gr * NF + f0] = o;
        }
    }
}

// --------------- gather1: out1[c] = bg1 + h1[c]*dinv^2 + sum_e w*h1[src]
__global__ __launch_bounds__(256) void gather1_kernel(
    const int* __restrict__ offs, const int* __restrict__ src,
    const float* __restrict__ wgt, const float* __restrict__ h1,
    const float* __restrict__ dinv, const float* __restrict__ bg1,
    float* __restrict__ out1, int N)
{
    int wid  = threadIdx.x >> 6;
    int lane = threadIdx.x & 63;
    int c = blockIdx.x * 4 + wid;
    if (c >= N) return;
    float di = dinv[c];
    float2 hv = *(const float2*)(h1 + (size_t)c * NF + 2 * lane);
    float2 acc;
    acc.x = bg1[2 * lane]     + hv.x * di * di;
    acc.y = bg1[2 * lane + 1] + hv.y * di * di;

    int beg = offs[c], end = offs[c + 1];
    for (int e0 = beg; e0 < end; e0 += 64) {
        int idx = e0 + lane;
        int   sv = 0; float wv = 0.0f;
        if (idx < end) { sv = src[idx]; wv = wgt[idx]; }
        int m = end - e0; if (m > 64) m = 64;
        for (int j = 0; j < m; j++) {
            int   s = __shfl(sv, j);
            float w = __shfl(wv, j);
            float2 v = *(const float2*)(h1 + (size_t)s * NF + 2 * lane);
            acc.x += w * v.x;
            acc.y += w * v.y;
        }
    }
    *(float2*)(out1 + (size_t)c * NF + 2 * lane) = acc;
}

// ----------------------- GEMM2: h2 = relu(out1) @ Wg2  (128 -> 40)
#define G2_ROWS 64
__global__ __launch_bounds__(256) void gemm2_kernel(
    const float* __restrict__ out1, const float* __restrict__ W,
    float* __restrict__ h2, int N)
{
    __shared__ float sW[NF * NCLS];
    __shared__ float sx[NF * XPAD];
    int t = threadIdx.x;
    for (int i = t; i < NF * NCLS; i += 256) sW[i] = W[i];
    int row0 = blockIdx.x * G2_ROWS;
    for (int i = t; i < G2_ROWS * NF; i += 256) {
        int r = i >> 7, k = i & 127;
        int gr = row0 + r;
        sx[k * XPAD + r] = (gr < N) ? fmaxf(out1[(size_t)gr * NF + k], 0.0f) : 0.0f;
    }
    __syncthreads();

    int fg = t & 15, rg = t >> 4;
    int f0 = fg * 4;
    int f0c = (f0 <= NCLS - 4) ? f0 : (NCLS - 4);
    int r0 = rg * 4;
    float acc[4][4];
    #pragma unroll
    for (int r = 0; r < 4; r++)
        #pragma unroll
        for (int c = 0; c < 4; c++) acc[r][c] = 0.0f;

    #pragma unroll 8
    for (int k = 0; k < NF; k++) {
        float4 w  = *(const float4*)&sW[k * NCLS + f0c];
        float4 xa = *(const float4*)&sx[k * XPAD + r0];
        float xr[4] = {xa.x, xa.y, xa.z, xa.w};
        #pragma unroll
        for (int r = 0; r < 4; r++) {
            acc[r][0] += xr[r] * w.x;
            acc[r][1] += xr[r] * w.y;
            acc[r][2] += xr[r] * w.z;
            acc[r][3] += xr[r] * w.w;
        }
    }
    if (f0 <= NCLS - 4) {
        #pragma unroll
        for (int r = 0; r < 4; r++) {
            int gr = row0 + r0 + r;
            if (gr < N) {
                #pragma unroll
                for (int c = 0; c < 4; c++) h2[(size_t)gr * NCLS + f0 + c] = acc[r][c];
            }
        }
    }
}

// --------------- gather2: out[c] = bg2 + h2[c]*dinv^2 + sum_e w*h2[src]
__global__ __launch_bounds__(256) void gather2_kernel(
    const int* __restrict__ offs, const int* __restrict__ src,
    const float* __restrict__ wgt, const float* __restrict__ h2,
    const float* __restrict__ dinv, const float* __restrict__ bg2,
    float* __restrict__ out, int N)
{
    int wid  = threadIdx.x >> 6;
    int lane = threadIdx.x & 63;
    int c = blockIdx.x * 4 + wid;
    if (c >= N) return;
    float di = dinv[c];
    float acc = 0.0f;
    if (lane < NCLS) acc = bg2[lane] + h2[(size_t)c * NCLS + lane] * di * di;

    int beg = offs[c], end = offs[c + 1];
    for (int e0 = beg; e0 < end; e0 += 64) {
        int idx = e0 + lane;
        int   sv = 0; float wv = 0.0f;
        if (idx < end) { sv = src[idx]; wv = wgt[idx]; }
        int m = end - e0; if (m > 64) m = 64;
        for (int j = 0; j < m; j++) {
            int   s = __shfl(sv, j);
            float w = __shfl(wv, j);
            if (lane < NCLS) acc += w * h2[(size_t)s * NCLS + lane];
        }
    }
    if (lane < NCLS) out[(size_t)c * NCLS + lane] = acc;
}

// ============================================================== launch
extern "C" void kernel_launch(void* const* d_in, const int* in_sizes, int n_in,
                              void* d_out, int out_size, void* d_ws, size_t ws_size,
                              hipStream_t stream)
{
    const float* x   = (const float*)d_in[0];
    const int*   ei  = (const int*)d_in[1];
    const float* exf = (const float*)d_in[2];
    const float* W1  = (const float*)d_in[3];
    const float* b1  = (const float*)d_in[4];
    const float* W2  = (const float*)d_in[5];
    const float* b2  = (const float*)d_in[6];
    const float* Wg1 = (const float*)d_in[7];
    const float* bg1 = (const float*)d_in[8];
    const float* Wg2 = (const float*)d_in[9];
    const float* bg2 = (const float*)d_in[10];
    float* out = (float*)d_out;

    int N = in_sizes[0] / NF;
    int E = in_sizes[2] / EF;
    const int* row = ei;
    const int* col = ei + E;
    int ntiles = (E + TILE - 1) / TILE;
    int L = 256 * ntiles;

    // workspace bump allocator (4-byte words)
    char* base = (char*)d_ws;
    size_t off = 0;
    auto alloc = [&](size_t words) -> void* {
        void* p = base + off * 4;
        off += (words + 3) & ~(size_t)3;
        return p;
    };
    // region A: ew + pass1 output (4E words) -- later reused as h1 / h2
    size_t awords = (size_t)4 * E;
    size_t h1words = (size_t)N * NF;
    if (h1words > awords) awords = h1words;
    float* regA = (float*)alloc(awords);
    float* ew   = regA;
    int*   keyS = (int*)(regA + E);
    int*   srcS = (int*)(regA + 2 * (size_t)E);
    float* ewS  = regA + 3 * (size_t)E;
    float* h1   = regA;                      // alias (after sort consumed)
    float* h2   = regA;                      // alias (after gather1 consumed)
    // region B: final CSR
    int*   srcF = (int*)  alloc(E);
    float* wgtF = (float*)alloc(E);
    // region C: out1
    float* out1 = (float*)alloc((size_t)N * NF);
    // region D: small
    float* dinv = (float*)alloc(N);
    int*   offs = (int*)  alloc(N + 1);
    int*   hist = (int*)  alloc(L);
    int*   dtot = (int*)  alloc(256);
    int*   dbase= (int*)  alloc(257);

    int nb;
    nb = (E + 255) / 256;
    edge_mlp_kernel<<<nb, 256, 0, stream>>>(exf, W1, b1, W2, b2, ew, E);

    hist1_kernel<<<ntiles, 256, 0, stream>>>(col, hist, E, ntiles);
    scanA_kernel<<<256, 256, 0, stream>>>(hist, dtot, ntiles);
    scanB_kernel<<<1, 256, 0, stream>>>(dtot, dbase, E);
    scatter1_kernel<<<ntiles, 256, 0, stream>>>(row, col, ew, hist, dbase,
                                                keyS, srcS, ewS, E, ntiles);
    bucket_sort_kernel<<<256, 512, 0, stream>>>(keyS, srcS, ewS, dbase,
                                                srcF, wgtF, offs, dinv, E, N);
    nb = (E + 255) / 256;
    normalize_kernel<<<nb, 256, 0, stream>>>(srcF, wgtF, dinv, E);

    nb = (N + G1_ROWS - 1) / G1_ROWS;
    gemm1_kernel<<<nb, 256, 0, stream>>>(x, Wg1, h1, N);

    nb = (N + 3) / 4;
    gather1_kernel<<<nb, 256, 0, stream>>>(offs, srcF, wgtF, h1, dinv, bg1, out1, N);

    nb = (N + G2_ROWS - 1) / G2_ROWS;
    gemm2_kernel<<<nb, 256, 0, stream>>>(out1, Wg2, h2, N);

    nb = (N + 3) / 4;
    gather2_kernel<<<nb, 256, 0, stream>>>(offs, srcF, wgtF, h2, dinv, bg2, out, N);
}

// Round 5
// 588.661 us; speedup vs baseline: 5.6583x; 1.1091x over previous
//
#include <hip/hip_runtime.h>
#include <hip/hip_bf16.h>
#include <math.h>

//  x:        [N,128] f32      (in 0)
//  edge_index[2,E]   i32      (in 1)
//  edge_x:   [E,16]  f32      (in 2)
//  W1 [16,32] b1[32] W2[32,1] b2[1]   (in 3..6)
//  Wg1[128,128] bg1[128] Wg2[128,40] bg2[40]  (in 7..10)
//  out:      [N,40]  f32

#define NF   128
#define EF   16
#define EFIL 32
#define NCLS 40
#define TILE 4096   // edges per tile for pass-1 sort

// -------------------------- edge MLP (pure compute, no atomics)
__global__ __launch_bounds__(256) void edge_mlp_kernel(
    const float* __restrict__ ex, const float* __restrict__ W1,
    const float* __restrict__ b1, const float* __restrict__ W2,
    const float* __restrict__ b2, float* __restrict__ ew, int E)
{
    __shared__ float sW1[EF * EFIL];
    __shared__ float sb1[EFIL];
    __shared__ float sW2[EFIL];
    __shared__ float sb2;
    int t = threadIdx.x;
    for (int i = t; i < EF * EFIL; i += 256) sW1[i] = W1[i];
    if (t < EFIL) { sb1[t] = b1[t]; sW2[t] = W2[t]; }
    if (t == 0) sb2 = b2[0];
    __syncthreads();

    int e = blockIdx.x * 256 + t;
    if (e >= E) return;

    float xv[EF];
    const float4* exv = (const float4*)(ex) + (size_t)e * (EF / 4);
    #pragma unroll
    for (int q = 0; q < EF / 4; q++) {
        float4 v = exv[q];
        xv[q * 4 + 0] = v.x; xv[q * 4 + 1] = v.y;
        xv[q * 4 + 2] = v.z; xv[q * 4 + 3] = v.w;
    }
    float acc = sb2;
    #pragma unroll
    for (int j = 0; j < EFIL; j++) {
        float h = sb1[j];
        #pragma unroll
        for (int k = 0; k < EF; k++) h += xv[k] * sW1[k * EFIL + j];
        acc += fmaxf(h, 0.0f) * sW2[j];
    }
    ew[e] = 1.0f / (1.0f + expf(-acc));
}

// -------------------- pass1 histogram: digit = col>>8, LDS only
__global__ __launch_bounds__(256) void hist1_kernel(
    const int* __restrict__ col, int* __restrict__ hist, int E, int ntiles)
{
    __shared__ int h[256];
    int t = threadIdx.x;
    h[t] = 0;
    __syncthreads();
    int tile = blockIdx.x;
    int base = tile * TILE;
    int end = base + TILE; if (end > E) end = E;
    for (int i = base + t; i < end; i += 256)
        atomicAdd(&h[col[i] >> 8], 1);
    __syncthreads();
    hist[t * ntiles + tile] = h[t];
}

// ---- scanA: one block per digit; exclusive scan of hist[d][0..ntiles) in
//      place (digit-major, coalesced), digit total -> dtot[d]
__global__ __launch_bounds__(256) void scanA_kernel(
    int* __restrict__ hist, int* __restrict__ dtot, int ntiles)
{
    __shared__ int ts[256];
    int d = blockIdx.x;
    int t = threadIdx.x;
    int* hrow = hist + (size_t)d * ntiles;
    int C = (ntiles + 255) >> 8;
    int b = t * C;
    int e = b + C; if (e > ntiles) e = ntiles;
    int s = 0;
    for (int i = b; i < e; i++) s += hrow[i];
    ts[t] = s;
    __syncthreads();
    for (int dd = 1; dd < 256; dd <<= 1) {
        int v = (t >= dd) ? ts[t - dd] : 0;
        __syncthreads();
        ts[t] += v;
        __syncthreads();
    }
    int run = ts[t] - s;   // exclusive prefix of this thread's chunk
    for (int i = b; i < e; i++) {
        int v = hrow[i];
        hrow[i] = run;     // in-place exclusive within-digit prefix
        run += v;
    }
    if (t == 255) dtot[d] = ts[255];
}

// ---- scanB: exclusive scan of 256 digit totals -> dbase[0..256]
__global__ __launch_bounds__(256) void scanB_kernel(
    const int* __restrict__ dtot, int* __restrict__ dbase, int E)
{
    __shared__ int ts[256];
    int t = threadIdx.x;
    int s = dtot[t];
    ts[t] = s;
    __syncthreads();
    for (int dd = 1; dd < 256; dd <<= 1) {
        int v = (t >= dd) ? ts[t - dd] : 0;
        __syncthreads();
        ts[t] += v;
        __syncthreads();
    }
    dbase[t] = ts[t] - s;
    if (t == 255) dbase[256] = E;
}

// -------------------- pass1 scatter: bucket by col>>8 (unstable, LDS cursors)
__global__ __launch_bounds__(256) void scatter1_kernel(
    const int* __restrict__ row, const int* __restrict__ col,
    const float* __restrict__ ew, const int* __restrict__ hscan,
    const int* __restrict__ dbase,
    int* __restrict__ keyS, int* __restrict__ srcS, float* __restrict__ ewS,
    int E, int ntiles)
{
    __shared__ int cur[256];
    int t = threadIdx.x;
    int tile = blockIdx.x;
    cur[t] = dbase[t] + hscan[t * ntiles + tile];
    __syncthreads();
    int base = tile * TILE;
    int end = base + TILE; if (end > E) end = E;
    for (int i = base + t; i < end; i += 256) {
        int c = col[i];
        int p = atomicAdd(&cur[c >> 8], 1);
        keyS[p] = c;
        srcS[p] = row[i];
        ewS[p] = ew[i];
    }
}

// ---- pass2: per-bucket counting sort by col&255 + offs + deg/dinv (fused)
__global__ __launch_bounds__(512) void bucket_sort_kernel(
    const int* __restrict__ keyS, const int* __restrict__ srcS,
    const float* __restrict__ ewS, const int* __restrict__ dbase,
    int* __restrict__ srcF, float* __restrict__ wgtF,
    int* __restrict__ offs, float* __restrict__ dinv,
    int E, int N)
{
    __shared__ int   cnt[256];
    __shared__ int   scan[256];
    __shared__ int   cursor[256];
    __shared__ float dsum[256];
    __shared__ float sdinv[256];
    int t = threadIdx.x;
    int b = blockIdx.x;
    if (t == 0 && b == 0) offs[N] = E;
    int bstart = dbase[b];
    int bend   = dbase[b + 1];
    if (t < 256) { cnt[t] = 0; dsum[t] = 0.0f; sdinv[t] = 0.0f; }
    __syncthreads();
    for (int i = bstart + t; i < bend; i += 512) {
        int lo = keyS[i] & 255;
        atomicAdd(&cnt[lo], 1);
        atomicAdd(&dsum[lo], ewS[i]);
    }
    __syncthreads();
    if (t < 256) scan[t] = cnt[t];
    __syncthreads();
    for (int d = 1; d < 256; d <<= 1) {
        int v = 0;
        if (t < 256 && t >= d) v = scan[t - d];
        __syncthreads();
        if (t < 256) scan[t] += v;
        __syncthreads();
    }
    if (t < 256) {
        int excl = scan[t] - cnt[t];
        int c = (b << 8) + t;
        cursor[t] = bstart + excl;
        if (c < N) {
            offs[c] = bstart + excl;
            float deg = 1.0f + dsum[t];
            float di = rsqrtf(deg);
            sdinv[t] = di;
            dinv[c] = di;
        }
    }
    __syncthreads();
    for (int i = bstart + t; i < bend; i += 512) {
        int k = keyS[i];
        int lo = k & 255;
        int p = atomicAdd(&cursor[lo], 1);
        srcF[p] = srcS[i];
        wgtF[p] = ewS[i] * sdinv[lo];   // * dinv[col]; dinv[src] folded into h'
    }
}

// ------------------- GEMM1: h1' = (x @ Wg1) * dinv[row]  (128->128)
#define G1_ROWS 64
#define XPAD 68
__global__ __launch_bounds__(256) void gemm1_kernel(
    const float* __restrict__ x, const float* __restrict__ W,
    const float* __restrict__ dinv, float* __restrict__ h1, int N)
{
    __shared__ float sW[NF * NF];
    __shared__ float sx[NF * XPAD];
    int t = threadIdx.x;
    for (int i = t; i < NF * NF; i += 256) sW[i] = W[i];
    int row0 = blockIdx.x * G1_ROWS;
    for (int i = t; i < G1_ROWS * NF; i += 256) {
        int r = i >> 7, k = i & 127;
        int gr = row0 + r;
        sx[k * XPAD + r] = (gr < N) ? x[(size_t)gr * NF + k] : 0.0f;
    }
    __syncthreads();

    int fg = t & 31, rg = t >> 5;
    int f0 = fg * 4, r0 = rg * 8;
    float acc[8][4];
    #pragma unroll
    for (int r = 0; r < 8; r++)
        #pragma unroll
        for (int c = 0; c < 4; c++) acc[r][c] = 0.0f;

    #pragma unroll 8
    for (int k = 0; k < NF; k++) {
        float4 w  = *(const float4*)&sW[k * NF + f0];
        float4 xa = *(const float4*)&sx[k * XPAD + r0];
        float4 xb = *(const float4*)&sx[k * XPAD + r0 + 4];
        float xr[8] = {xa.x, xa.y, xa.z, xa.w, xb.x, xb.y, xb.z, xb.w};
        #pragma unroll
        for (int r = 0; r < 8; r++) {
            acc[r][0] += xr[r] * w.x;
            acc[r][1] += xr[r] * w.y;
            acc[r][2] += xr[r] * w.z;
            acc[r][3] += xr[r] * w.w;
        }
    }
    #pragma unroll
    for (int r = 0; r < 8; r++) {
        int gr = row0 + r0 + r;
        if (gr < N) {
            float di = dinv[gr];
            float4 o = {acc[r][0] * di, acc[r][1] * di, acc[r][2] * di, acc[r][3] * di};
            *(float4*)&h1[(size_t)gr * NF + f0] = o;
        }
    }
}

// --------------- gather1: out1[c] = bg1 + h1'[c]*di + sum_e w*h1'[src]
// one wave per node; 64 lanes x float2; inner loop unrolled x8 for MLP
__global__ __launch_bounds__(256) void gather1_kernel(
    const int* __restrict__ offs, const int* __restrict__ src,
    const float* __restrict__ wgt, const float* __restrict__ h1,
    const float* __restrict__ dinv, const float* __restrict__ bg1,
    float* __restrict__ out1, int N)
{
    int wid  = threadIdx.x >> 6;
    int lane = threadIdx.x & 63;
    int c = blockIdx.x * 4 + wid;
    if (c >= N) return;
    float di = dinv[c];
    float2 hv = *(const float2*)(h1 + (size_t)c * NF + 2 * lane);
    float2 acc;
    acc.x = bg1[2 * lane]     + hv.x * di;   // h1' already has one dinv factor
    acc.y = bg1[2 * lane + 1] + hv.y * di;

    int beg = offs[c], end = offs[c + 1];
    for (int e0 = beg; e0 < end; e0 += 64) {
        int idx = e0 + lane;
        int   sv = 0; float wv = 0.0f;
        if (idx < end) { sv = src[idx]; wv = wgt[idx]; }
        int m = end - e0; if (m > 64) m = 64;
        int j = 0;
        for (; j + 8 <= m; j += 8) {
            float2 v[8]; float w[8];
            #pragma unroll
            for (int u = 0; u < 8; u++) {
                int s = __shfl(sv, j + u);
                w[u] = __shfl(wv, j + u);
                v[u] = *(const float2*)(h1 + (size_t)s * NF + 2 * lane);
            }
            #pragma unroll
            for (int u = 0; u < 8; u++) {
                acc.x += w[u] * v[u].x;
                acc.y += w[u] * v[u].y;
            }
        }
        for (; j < m; j++) {
            int   s = __shfl(sv, j);
            float w = __shfl(wv, j);
            float2 v = *(const float2*)(h1 + (size_t)s * NF + 2 * lane);
            acc.x += w * v.x;
            acc.y += w * v.y;
        }
    }
    *(float2*)(out1 + (size_t)c * NF + 2 * lane) = acc;
}

// ----------------- GEMM2: h2' = (relu(out1) @ Wg2) * dinv[row]  (128 -> 40)
#define G2_ROWS 64
__global__ __launch_bounds__(256) void gemm2_kernel(
    const float* __restrict__ out1, const float* __restrict__ W,
    const float* __restrict__ dinv, float* __restrict__ h2, int N)
{
    __shared__ float sW[NF * NCLS];
    __shared__ float sx[NF * XPAD];
    int t = threadIdx.x;
    for (int i = t; i < NF * NCLS; i += 256) sW[i] = W[i];
    int row0 = blockIdx.x * G2_ROWS;
    for (int i = t; i < G2_ROWS * NF; i += 256) {
        int r = i >> 7, k = i & 127;
        int gr = row0 + r;
        sx[k * XPAD + r] = (gr < N) ? fmaxf(out1[(size_t)gr * NF + k], 0.0f) : 0.0f;
    }
    __syncthreads();

    int fg = t & 15, rg = t >> 4;
    int f0 = fg * 4;
    int f0c = (f0 <= NCLS - 4) ? f0 : (NCLS - 4);
    int r0 = rg * 4;
    float acc[4][4];
    #pragma unroll
    for (int r = 0; r < 4; r++)
        #pragma unroll
        for (int c = 0; c < 4; c++) acc[r][c] = 0.0f;

    #pragma unroll 8
    for (int k = 0; k < NF; k++) {
        float4 w  = *(const float4*)&sW[k * NCLS + f0c];
        float4 xa = *(const float4*)&sx[k * XPAD + r0];
        float xr[4] = {xa.x, xa.y, xa.z, xa.w};
        #pragma unroll
        for (int r = 0; r < 4; r++) {
            acc[r][0] += xr[r] * w.x;
            acc[r][1] += xr[r] * w.y;
            acc[r][2] += xr[r] * w.z;
            acc[r][3] += xr[r] * w.w;
        }
    }
    if (f0 <= NCLS - 4) {
        #pragma unroll
        for (int r = 0; r < 4; r++) {
            int gr = row0 + r0 + r;
            if (gr < N) {
                float di = dinv[gr];
                #pragma unroll
                for (int c = 0; c < 4; c++) h2[(size_t)gr * NCLS + f0 + c] = acc[r][c] * di;
            }
        }
    }
}

// --------------- gather2: out[c] = bg2 + h2'[c]*di + sum_e w*h2'[src]
__global__ __launch_bounds__(256) void gather2_kernel(
    const int* __restrict__ offs, const int* __restrict__ src,
    const float* __restrict__ wgt, const float* __restrict__ h2,
    const float* __restrict__ dinv, const float* __restrict__ bg2,
    float* __restrict__ out, int N)
{
    int wid  = threadIdx.x >> 6;
    int lane = threadIdx.x & 63;
    int c = blockIdx.x * 4 + wid;
    if (c >= N) return;
    float di = dinv[c];
    float acc = 0.0f;
    if (lane < NCLS) acc = bg2[lane] + h2[(size_t)c * NCLS + lane] * di;

    int beg = offs[c], end = offs[c + 1];
    for (int e0 = beg; e0 < end; e0 += 64) {
        int idx = e0 + lane;
        int   sv = 0; float wv = 0.0f;
        if (idx < end) { sv = src[idx]; wv = wgt[idx]; }
        int m = end - e0; if (m > 64) m = 64;
        int j = 0;
        for (; j + 8 <= m; j += 8) {
            float v[8]; float w[8];
            #pragma unroll
            for (int u = 0; u < 8; u++) {
                int s = __shfl(sv, j + u);
                w[u] = __shfl(wv, j + u);
                v[u] = (lane < NCLS) ? h2[(size_t)s * NCLS + lane] : 0.0f;
            }
            #pragma unroll
            for (int u = 0; u < 8; u++) acc += w[u] * v[u];
        }
        for (; j < m; j++) {
            int   s = __shfl(sv, j);
            float w = __shfl(wv, j);
            if (lane < NCLS) acc += w * h2[(size_t)s * NCLS + lane];
        }
    }
    if (lane < NCLS) out[(size_t)c * NCLS + lane] = acc;
}

// ============================================================== launch
extern "C" void kernel_launch(void* const* d_in, const int* in_sizes, int n_in,
                              void* d_out, int out_size, void* d_ws, size_t ws_size,
                              hipStream_t stream)
{
    const float* x   = (const float*)d_in[0];
    const int*   ei  = (const int*)d_in[1];
    const float* exf = (const float*)d_in[2];
    const float* W1  = (const float*)d_in[3];
    const float* b1  = (const float*)d_in[4];
    const float* W2  = (const float*)d_in[5];
    const float* b2  = (const float*)d_in[6];
    const float* Wg1 = (const float*)d_in[7];
    const float* bg1 = (const float*)d_in[8];
    const float* Wg2 = (const float*)d_in[9];
    const float* bg2 = (const float*)d_in[10];
    float* out = (float*)d_out;

    int N = in_sizes[0] / NF;
    int E = in_sizes[2] / EF;
    const int* row = ei;
    const int* col = ei + E;
    int ntiles = (E + TILE - 1) / TILE;
    int L = 256 * ntiles;

    // workspace bump allocator (4-byte words)
    char* base = (char*)d_ws;
    size_t off = 0;
    auto alloc = [&](size_t words) -> void* {
        void* p = base + off * 4;
        off += (words + 3) & ~(size_t)3;
        return p;
    };
    // region A: ew + pass1 output (4E words) -- later reused as h1 / h2
    size_t awords = (size_t)4 * E;
    size_t h1words = (size_t)N * NF;
    if (h1words > awords) awords = h1words;
    float* regA = (float*)alloc(awords);
    float* ew   = regA;
    int*   keyS = (int*)(regA + E);
    int*   srcS = (int*)(regA + 2 * (size_t)E);
    float* ewS  = regA + 3 * (size_t)E;
    float* h1   = regA;                      // alias (after sort consumed)
    float* h2   = regA;                      // alias (after gather1 consumed)
    // region B: final CSR
    int*   srcF = (int*)  alloc(E);
    float* wgtF = (float*)alloc(E);
    // region C: out1
    float* out1 = (float*)alloc((size_t)N * NF);
    // region D: small
    float* dinv = (float*)alloc(N);
    int*   offs = (int*)  alloc(N + 1);
    int*   hist = (int*)  alloc(L);
    int*   dtot = (int*)  alloc(256);
    int*   dbase= (int*)  alloc(257);

    int nb;
    nb = (E + 255) / 256;
    edge_mlp_kernel<<<nb, 256, 0, stream>>>(exf, W1, b1, W2, b2, ew, E);

    hist1_kernel<<<ntiles, 256, 0, stream>>>(col, hist, E, ntiles);
    scanA_kernel<<<256, 256, 0, stream>>>(hist, dtot, ntiles);
    scanB_kernel<<<1, 256, 0, stream>>>(dtot, dbase, E);
    scatter1_kernel<<<ntiles, 256, 0, stream>>>(row, col, ew, hist, dbase,
                                                keyS, srcS, ewS, E, ntiles);
    bucket_sort_kernel<<<256, 512, 0, stream>>>(keyS, srcS, ewS, dbase,
                                                srcF, wgtF, offs, dinv, E, N);

    nb = (N + G1_ROWS - 1) / G1_ROWS;
    gemm1_kernel<<<nb, 256, 0, stream>>>(x, Wg1, dinv, h1, N);

    nb = (N + 3) / 4;
    gather1_kernel<<<nb, 256, 0, stream>>>(offs, srcF, wgtF, h1, dinv, bg1, out1, N);

    nb = (N + G2_ROWS - 1) / G2_ROWS;
    gemm2_kernel<<<nb, 256, 0, stream>>>(out1, Wg2, dinv, h2, N);

    nb = (N + 3) / 4;
    gather2_kernel<<<nb, 256, 0, stream>>>(offs, srcF, wgtF, h2, dinv, bg2, out, N);
}

// Round 6
// 526.998 us; speedup vs baseline: 6.3203x; 1.1170x over previous
//
#include <hip/hip_runtime.h>
#include <hip/hip_bf16.h>
#include <math.h>

//  x:        [N,128] f32      (in 0)
//  edge_index[2,E]   i32      (in 1)
//  edge_x:   [E,16]  f32      (in 2)
//  W1 [16,32] b1[32] W2[32,1] b2[1]   (in 3..6)
//  Wg1[128,128] bg1[128] Wg2[128,40] bg2[40]  (in 7..10)
//  out:      [N,40]  f32

#define NF   128
#define EF   16
#define EFIL 32
#define NCLS 40
#define TILE 4096   // edges per tile for pass-1 sort

// -------------------------- edge MLP (pure compute, no atomics)
__global__ __launch_bounds__(256) void edge_mlp_kernel(
    const float* __restrict__ ex, const float* __restrict__ W1,
    const float* __restrict__ b1, const float* __restrict__ W2,
    const float* __restrict__ b2, float* __restrict__ ew, int E)
{
    __shared__ float sW1[EF * EFIL];
    __shared__ float sb1[EFIL];
    __shared__ float sW2[EFIL];
    __shared__ float sb2;
    int t = threadIdx.x;
    for (int i = t; i < EF * EFIL; i += 256) sW1[i] = W1[i];
    if (t < EFIL) { sb1[t] = b1[t]; sW2[t] = W2[t]; }
    if (t == 0) sb2 = b2[0];
    __syncthreads();

    int e = blockIdx.x * 256 + t;
    if (e >= E) return;

    float xv[EF];
    const float4* exv = (const float4*)(ex) + (size_t)e * (EF / 4);
    #pragma unroll
    for (int q = 0; q < EF / 4; q++) {
        float4 v = exv[q];
        xv[q * 4 + 0] = v.x; xv[q * 4 + 1] = v.y;
        xv[q * 4 + 2] = v.z; xv[q * 4 + 3] = v.w;
    }
    float acc = sb2;
    #pragma unroll
    for (int j = 0; j < EFIL; j++) {
        float h = sb1[j];
        #pragma unroll
        for (int k = 0; k < EF; k++) h += xv[k] * sW1[k * EFIL + j];
        acc += fmaxf(h, 0.0f) * sW2[j];
    }
    ew[e] = 1.0f / (1.0f + expf(-acc));
}

// -------------------- pass1 histogram: digit = col>>8, LDS only
__global__ __launch_bounds__(256) void hist1_kernel(
    const int* __restrict__ col, int* __restrict__ hist, int E, int ntiles)
{
    __shared__ int h[256];
    int t = threadIdx.x;
    h[t] = 0;
    __syncthreads();
    int tile = blockIdx.x;
    int base = tile * TILE;
    int end = base + TILE; if (end > E) end = E;
    for (int i = base + t; i < end; i += 256)
        atomicAdd(&h[col[i] >> 8], 1);
    __syncthreads();
    hist[t * ntiles + tile] = h[t];
}

// ---- scanA: one block per digit; exclusive scan of hist[d][0..ntiles) in
//      place (digit-major, coalesced), digit total -> dtot[d]
__global__ __launch_bounds__(256) void scanA_kernel(
    int* __restrict__ hist, int* __restrict__ dtot, int ntiles)
{
    __shared__ int ts[256];
    int d = blockIdx.x;
    int t = threadIdx.x;
    int* hrow = hist + (size_t)d * ntiles;
    int C = (ntiles + 255) >> 8;
    int b = t * C;
    int e = b + C; if (e > ntiles) e = ntiles;
    int s = 0;
    for (int i = b; i < e; i++) s += hrow[i];
    ts[t] = s;
    __syncthreads();
    for (int dd = 1; dd < 256; dd <<= 1) {
        int v = (t >= dd) ? ts[t - dd] : 0;
        __syncthreads();
        ts[t] += v;
        __syncthreads();
    }
    int run = ts[t] - s;   // exclusive prefix of this thread's chunk
    for (int i = b; i < e; i++) {
        int v = hrow[i];
        hrow[i] = run;     // in-place exclusive within-digit prefix
        run += v;
    }
    if (t == 255) dtot[d] = ts[255];
}

// ---- scanB: exclusive scan of 256 digit totals -> dbase[0..256]
__global__ __launch_bounds__(256) void scanB_kernel(
    const int* __restrict__ dtot, int* __restrict__ dbase, int E)
{
    __shared__ int ts[256];
    int t = threadIdx.x;
    int s = dtot[t];
    ts[t] = s;
    __syncthreads();
    for (int dd = 1; dd < 256; dd <<= 1) {
        int v = (t >= dd) ? ts[t - dd] : 0;
        __syncthreads();
        ts[t] += v;
        __syncthreads();
    }
    dbase[t] = ts[t] - s;
    if (t == 255) dbase[256] = E;
}

// -------------------- pass1 scatter: bucket by col>>8 (unstable, LDS cursors)
__global__ __launch_bounds__(256) void scatter1_kernel(
    const int* __restrict__ row, const int* __restrict__ col,
    const float* __restrict__ ew, const int* __restrict__ hscan,
    const int* __restrict__ dbase,
    int* __restrict__ keyS, int* __restrict__ srcS, float* __restrict__ ewS,
    int E, int ntiles)
{
    __shared__ int cur[256];
    int t = threadIdx.x;
    int tile = blockIdx.x;
    cur[t] = dbase[t] + hscan[t * ntiles + tile];
    __syncthreads();
    int base = tile * TILE;
    int end = base + TILE; if (end > E) end = E;
    for (int i = base + t; i < end; i += 256) {
        int c = col[i];
        int p = atomicAdd(&cur[c >> 8], 1);
        keyS[p] = c;
        srcS[p] = row[i];
        ewS[p] = ew[i];
    }
}

// ---- pass2: per-bucket counting sort by col&255 + offs + deg/dinv (fused)
__global__ __launch_bounds__(512) void bucket_sort_kernel(
    const int* __restrict__ keyS, const int* __restrict__ srcS,
    const float* __restrict__ ewS, const int* __restrict__ dbase,
    int* __restrict__ srcF, float* __restrict__ wgtF,
    int* __restrict__ offs, float* __restrict__ dinv,
    int E, int N)
{
    __shared__ int   cnt[256];
    __shared__ int   scan[256];
    __shared__ int   cursor[256];
    __shared__ float dsum[256];
    __shared__ float sdinv[256];
    int t = threadIdx.x;
    int b = blockIdx.x;
    if (t == 0 && b == 0) offs[N] = E;
    int bstart = dbase[b];
    int bend   = dbase[b + 1];
    if (t < 256) { cnt[t] = 0; dsum[t] = 0.0f; sdinv[t] = 0.0f; }
    __syncthreads();
    for (int i = bstart + t; i < bend; i += 512) {
        int lo = keyS[i] & 255;
        atomicAdd(&cnt[lo], 1);
        atomicAdd(&dsum[lo], ewS[i]);
    }
    __syncthreads();
    if (t < 256) scan[t] = cnt[t];
    __syncthreads();
    for (int d = 1; d < 256; d <<= 1) {
        int v = 0;
        if (t < 256 && t >= d) v = scan[t - d];
        __syncthreads();
        if (t < 256) scan[t] += v;
        __syncthreads();
    }
    if (t < 256) {
        int excl = scan[t] - cnt[t];
        int c = (b << 8) + t;
        cursor[t] = bstart + excl;
        if (c < N) {
            offs[c] = bstart + excl;
            float deg = 1.0f + dsum[t];
            float di = rsqrtf(deg);
            sdinv[t] = di;
            dinv[c] = di;
        }
    }
    __syncthreads();
    for (int i = bstart + t; i < bend; i += 512) {
        int k = keyS[i];
        int lo = k & 255;
        int p = atomicAdd(&cursor[lo], 1);
        srcF[p] = srcS[i];
        wgtF[p] = ewS[i] * sdinv[lo];   // * dinv[col]; dinv[src] folded into h'
    }
}

// ------------------- GEMM1: h1' = (x @ Wg1) * dinv[row]  (128->128)
// W read directly from global (64 KB, L2-resident, wave-coalesced float4).
// LDS holds only the transposed x tile -> 34.8 KB -> 4 blocks/CU.
#define G1_ROWS 64
#define XPAD 68
__global__ __launch_bounds__(256, 4) void gemm1_kernel(
    const float* __restrict__ x, const float* __restrict__ W,
    const float* __restrict__ dinv, float* __restrict__ h1, int N)
{
    __shared__ float sx[NF * XPAD];        // sx[k*XPAD + r]
    int t = threadIdx.x;
    int row0 = blockIdx.x * G1_ROWS;
    for (int i = t; i < G1_ROWS * NF; i += 256) {
        int r = i >> 7, k = i & 127;
        int gr = row0 + r;
        sx[k * XPAD + r] = (gr < N) ? x[(size_t)gr * NF + k] : 0.0f;
    }
    __syncthreads();

    int fg = t & 31, rg = t >> 5;
    int f0 = fg * 4, r0 = rg * 8;
    float acc[8][4];
    #pragma unroll
    for (int r = 0; r < 8; r++)
        #pragma unroll
        for (int c = 0; c < 4; c++) acc[r][c] = 0.0f;

    #pragma unroll 8
    for (int k = 0; k < NF; k++) {
        float4 w  = *(const float4*)&W[(size_t)k * NF + f0];
        float4 xa = *(const float4*)&sx[k * XPAD + r0];
        float4 xb = *(const float4*)&sx[k * XPAD + r0 + 4];
        float xr[8] = {xa.x, xa.y, xa.z, xa.w, xb.x, xb.y, xb.z, xb.w};
        #pragma unroll
        for (int r = 0; r < 8; r++) {
            acc[r][0] += xr[r] * w.x;
            acc[r][1] += xr[r] * w.y;
            acc[r][2] += xr[r] * w.z;
            acc[r][3] += xr[r] * w.w;
        }
    }
    #pragma unroll
    for (int r = 0; r < 8; r++) {
        int gr = row0 + r0 + r;
        if (gr < N) {
            float di = dinv[gr];
            float4 o = {acc[r][0] * di, acc[r][1] * di, acc[r][2] * di, acc[r][3] * di};
            *(float4*)&h1[(size_t)gr * NF + f0] = o;
        }
    }
}

// --------------- gather1: out1[c] = bg1 + h1'[c]*di + sum_e w*h1'[src]
// one wave per node; 64 lanes x float2; inner loop unrolled x8 for MLP
__global__ __launch_bounds__(256) void gather1_kernel(
    const int* __restrict__ offs, const int* __restrict__ src,
    const float* __restrict__ wgt, const float* __restrict__ h1,
    const float* __restrict__ dinv, const float* __restrict__ bg1,
    float* __restrict__ out1, int N)
{
    int wid  = threadIdx.x >> 6;
    int lane = threadIdx.x & 63;
    int c = blockIdx.x * 4 + wid;
    if (c >= N) return;
    float di = dinv[c];
    float2 hv = *(const float2*)(h1 + (size_t)c * NF + 2 * lane);
    float2 acc;
    acc.x = bg1[2 * lane]     + hv.x * di;   // h1' already has one dinv factor
    acc.y = bg1[2 * lane + 1] + hv.y * di;

    int beg = offs[c], end = offs[c + 1];
    for (int e0 = beg; e0 < end; e0 += 64) {
        int idx = e0 + lane;
        int   sv = 0; float wv = 0.0f;
        if (idx < end) { sv = src[idx]; wv = wgt[idx]; }
        int m = end - e0; if (m > 64) m = 64;
        int j = 0;
        for (; j + 8 <= m; j += 8) {
            float2 v[8]; float w[8];
            #pragma unroll
            for (int u = 0; u < 8; u++) {
                int s = __shfl(sv, j + u);
                w[u] = __shfl(wv, j + u);
                v[u] = *(const float2*)(h1 + (size_t)s * NF + 2 * lane);
            }
            #pragma unroll
            for (int u = 0; u < 8; u++) {
                acc.x += w[u] * v[u].x;
                acc.y += w[u] * v[u].y;
            }
        }
        for (; j < m; j++) {
            int   s = __shfl(sv, j);
            float w = __shfl(wv, j);
            float2 v = *(const float2*)(h1 + (size_t)s * NF + 2 * lane);
            acc.x += w * v.x;
            acc.y += w * v.y;
        }
    }
    *(float2*)(out1 + (size_t)c * NF + 2 * lane) = acc;
}

// ----------------- GEMM2: h2' = (relu(out1) @ Wg2) * dinv[row]  (128 -> 40)
// W (20 KB) read directly from global/L2; LDS holds only the x tile.
#define G2_ROWS 64
__global__ __launch_bounds__(256, 4) void gemm2_kernel(
    const float* __restrict__ out1, const float* __restrict__ W,
    const float* __restrict__ dinv, float* __restrict__ h2, int N)
{
    __shared__ float sx[NF * XPAD];
    int t = threadIdx.x;
    int row0 = blockIdx.x * G2_ROWS;
    for (int i = t; i < G2_ROWS * NF; i += 256) {
        int r = i >> 7, k = i & 127;
        int gr = row0 + r;
        sx[k * XPAD + r] = (gr < N) ? fmaxf(out1[(size_t)gr * NF + k], 0.0f) : 0.0f;
    }
    __syncthreads();

    int fg = t & 15, rg = t >> 4;
    int f0 = fg * 4;
    int f0c = (f0 <= NCLS - 4) ? f0 : (NCLS - 4);
    int r0 = rg * 4;
    float acc[4][4];
    #pragma unroll
    for (int r = 0; r < 4; r++)
        #pragma unroll
        for (int c = 0; c < 4; c++) acc[r][c] = 0.0f;

    #pragma unroll 8
    for (int k = 0; k < NF; k++) {
        float4 w  = *(const float4*)&W[(size_t)k * NCLS + f0c];
        float4 xa = *(const float4*)&sx[k * XPAD + r0];
        float xr[4] = {xa.x, xa.y, xa.z, xa.w};
        #pragma unroll
        for (int r = 0; r < 4; r++) {
            acc[r][0] += xr[r] * w.x;
            acc[r][1] += xr[r] * w.y;
            acc[r][2] += xr[r] * w.z;
            acc[r][3] += xr[r] * w.w;
        }
    }
    if (f0 <= NCLS - 4) {
        #pragma unroll
        for (int r = 0; r < 4; r++) {
            int gr = row0 + r0 + r;
            if (gr < N) {
                float di = dinv[gr];
                #pragma unroll
                for (int c = 0; c < 4; c++) h2[(size_t)gr * NCLS + f0 + c] = acc[r][c] * di;
            }
        }
    }
}

// --------------- gather2: out[c] = bg2 + h2'[c]*di + sum_e w*h2'[src]
__global__ __launch_bounds__(256) void gather2_kernel(
    const int* __restrict__ offs, const int* __restrict__ src,
    const float* __restrict__ wgt, const float* __restrict__ h2,
    const float* __restrict__ dinv, const float* __restrict__ bg2,
    float* __restrict__ out, int N)
{
    int wid  = threadIdx.x >> 6;
    int lane = threadIdx.x & 63;
    int c = blockIdx.x * 4 + wid;
    if (c >= N) return;
    float di = dinv[c];
    float acc = 0.0f;
    if (lane < NCLS) acc = bg2[lane] + h2[(size_t)c * NCLS + lane] * di;

    int beg = offs[c], end = offs[c + 1];
    for (int e0 = beg; e0 < end; e0 += 64) {
        int idx = e0 + lane;
        int   sv = 0; float wv = 0.0f;
        if (idx < end) { sv = src[idx]; wv = wgt[idx]; }
        int m = end - e0; if (m > 64) m = 64;
        int j = 0;
        for (; j + 8 <= m; j += 8) {
            float v[8]; float w[8];
            #pragma unroll
            for (int u = 0; u < 8; u++) {
                int s = __shfl(sv, j + u);
                w[u] = __shfl(wv, j + u);
                v[u] = (lane < NCLS) ? h2[(size_t)s * NCLS + lane] : 0.0f;
            }
            #pragma unroll
            for (int u = 0; u < 8; u++) acc += w[u] * v[u];
        }
        for (; j < m; j++) {
            int   s = __shfl(sv, j);
            float w = __shfl(wv, j);
            if (lane < NCLS) acc += w * h2[(size_t)s * NCLS + lane];
        }
    }
    if (lane < NCLS) out[(size_t)c * NCLS + lane] = acc;
}

// ============================================================== launch
extern "C" void kernel_launch(void* const* d_in, const int* in_sizes, int n_in,
                              void* d_out, int out_size, void* d_ws, size_t ws_size,
                              hipStream_t stream)
{
    const float* x   = (const float*)d_in[0];
    const int*   ei  = (const int*)d_in[1];
    const float* exf = (const float*)d_in[2];
    const float* W1  = (const float*)d_in[3];
    const float* b1  = (const float*)d_in[4];
    const float* W2  = (const float*)d_in[5];
    const float* b2  = (const float*)d_in[6];
    const float* Wg1 = (const float*)d_in[7];
    const float* bg1 = (const float*)d_in[8];
    const float* Wg2 = (const float*)d_in[9];
    const float* bg2 = (const float*)d_in[10];
    float* out = (float*)d_out;

    int N = in_sizes[0] / NF;
    int E = in_sizes[2] / EF;
    const int* row = ei;
    const int* col = ei + E;
    int ntiles = (E + TILE - 1) / TILE;
    int L = 256 * ntiles;

    // workspace bump allocator (4-byte words)
    char* base = (char*)d_ws;
    size_t off = 0;
    auto alloc = [&](size_t words) -> void* {
        void* p = base + off * 4;
        off += (words + 3) & ~(size_t)3;
        return p;
    };
    // region A: ew + pass1 output (4E words) -- later reused as h1 / h2
    size_t awords = (size_t)4 * E;
    size_t h1words = (size_t)N * NF;
    if (h1words > awords) awords = h1words;
    float* regA = (float*)alloc(awords);
    float* ew   = regA;
    int*   keyS = (int*)(regA + E);
    int*   srcS = (int*)(regA + 2 * (size_t)E);
    float* ewS  = regA + 3 * (size_t)E;
    float* h1   = regA;                      // alias (after sort consumed)
    float* h2   = regA;                      // alias (after gather1 consumed)
    // region B: final CSR
    int*   srcF = (int*)  alloc(E);
    float* wgtF = (float*)alloc(E);
    // region C: out1
    float* out1 = (float*)alloc((size_t)N * NF);
    // region D: small
    float* dinv = (float*)alloc(N);
    int*   offs = (int*)  alloc(N + 1);
    int*   hist = (int*)  alloc(L);
    int*   dtot = (int*)  alloc(256);
    int*   dbase= (int*)  alloc(257);

    int nb;
    nb = (E + 255) / 256;
    edge_mlp_kernel<<<nb, 256, 0, stream>>>(exf, W1, b1, W2, b2, ew, E);

    hist1_kernel<<<ntiles, 256, 0, stream>>>(col, hist, E, ntiles);
    scanA_kernel<<<256, 256, 0, stream>>>(hist, dtot, ntiles);
    scanB_kernel<<<1, 256, 0, stream>>>(dtot, dbase, E);
    scatter1_kernel<<<ntiles, 256, 0, stream>>>(row, col, ew, hist, dbase,
                                                keyS, srcS, ewS, E, ntiles);
    bucket_sort_kernel<<<256, 512, 0, stream>>>(keyS, srcS, ewS, dbase,
                                                srcF, wgtF, offs, dinv, E, N);

    nb = (N + G1_ROWS - 1) / G1_ROWS;
    gemm1_kernel<<<nb, 256, 0, stream>>>(x, Wg1, dinv, h1, N);

    nb = (N + 3) / 4;
    gather1_kernel<<<nb, 256, 0, stream>>>(offs, srcF, wgtF, h1, dinv, bg1, out1, N);

    nb = (N + G2_ROWS - 1) / G2_ROWS;
    gemm2_kernel<<<nb, 256, 0, stream>>>(out1, Wg2, dinv, h2, N);

    nb = (N + 3) / 4;
    gather2_kernel<<<nb, 256, 0, stream>>>(offs, srcF, wgtF, h2, dinv, bg2, out, N);
}

// Round 7
// 475.809 us; speedup vs baseline: 7.0003x; 1.1076x over previous
//
#include <hip/hip_runtime.h>
#include <hip/hip_bf16.h>
#include <math.h>

//  x:        [N,128] f32      (in 0)
//  edge_index[2,E]   i32      (in 1)
//  edge_x:   [E,16]  f32      (in 2)
//  W1 [16,32] b1[32] W2[32,1] b2[1]   (in 3..6)
//  Wg1[128,128] bg1[128] Wg2[128,40] bg2[40]  (in 7..10)
//  out:      [N,40]  f32

#define NF   128
#define EF   16
#define EFIL 32
#define NCLS 40
#define TILE 4096   // edges per tile for pass-1 sort

// pack two fp32 -> 2xbf16 (RTNE), lo in low half
__device__ inline unsigned pack_bf16x2(float a, float b) {
    unsigned ua = __float_as_uint(a);
    unsigned ub = __float_as_uint(b);
    ua += 0x7FFF + ((ua >> 16) & 1);
    ub += 0x7FFF + ((ub >> 16) & 1);
    return (ua >> 16) | (ub & 0xFFFF0000u);
}
__device__ inline float bf16_lo(unsigned u) { return __uint_as_float(u << 16); }
__device__ inline float bf16_hi(unsigned u) { return __uint_as_float(u & 0xFFFF0000u); }

// -------------------------- edge MLP (pure compute, no atomics)
__global__ __launch_bounds__(256) void edge_mlp_kernel(
    const float* __restrict__ ex, const float* __restrict__ W1,
    const float* __restrict__ b1, const float* __restrict__ W2,
    const float* __restrict__ b2, float* __restrict__ ew, int E)
{
    __shared__ float sW1[EF * EFIL];
    __shared__ float sb1[EFIL];
    __shared__ float sW2[EFIL];
    __shared__ float sb2;
    int t = threadIdx.x;
    for (int i = t; i < EF * EFIL; i += 256) sW1[i] = W1[i];
    if (t < EFIL) { sb1[t] = b1[t]; sW2[t] = W2[t]; }
    if (t == 0) sb2 = b2[0];
    __syncthreads();

    int e = blockIdx.x * 256 + t;
    if (e >= E) return;

    float xv[EF];
    const float4* exv = (const float4*)(ex) + (size_t)e * (EF / 4);
    #pragma unroll
    for (int q = 0; q < EF / 4; q++) {
        float4 v = exv[q];
        xv[q * 4 + 0] = v.x; xv[q * 4 + 1] = v.y;
        xv[q * 4 + 2] = v.z; xv[q * 4 + 3] = v.w;
    }
    float acc = sb2;
    #pragma unroll
    for (int j = 0; j < EFIL; j++) {
        float h = sb1[j];
        #pragma unroll
        for (int k = 0; k < EF; k++) h += xv[k] * sW1[k * EFIL + j];
        acc += fmaxf(h, 0.0f) * sW2[j];
    }
    ew[e] = 1.0f / (1.0f + expf(-acc));
}

// -------------------- pass1 histogram: digit = col>>8, LDS only
__global__ __launch_bounds__(256) void hist1_kernel(
    const int* __restrict__ col, int* __restrict__ hist, int E, int ntiles)
{
    __shared__ int h[256];
    int t = threadIdx.x;
    h[t] = 0;
    __syncthreads();
    int tile = blockIdx.x;
    int base = tile * TILE;
    int end = base + TILE; if (end > E) end = E;
    for (int i = base + t; i < end; i += 256)
        atomicAdd(&h[col[i] >> 8], 1);
    __syncthreads();
    hist[t * ntiles + tile] = h[t];
}

// ---- scanA: one block per digit; exclusive scan of hist[d][0..ntiles) in
//      place (digit-major, coalesced), digit total -> dtot[d]
__global__ __launch_bounds__(256) void scanA_kernel(
    int* __restrict__ hist, int* __restrict__ dtot, int ntiles)
{
    __shared__ int ts[256];
    int d = blockIdx.x;
    int t = threadIdx.x;
    int* hrow = hist + (size_t)d * ntiles;
    int C = (ntiles + 255) >> 8;
    int b = t * C;
    int e = b + C; if (e > ntiles) e = ntiles;
    int s = 0;
    for (int i = b; i < e; i++) s += hrow[i];
    ts[t] = s;
    __syncthreads();
    for (int dd = 1; dd < 256; dd <<= 1) {
        int v = (t >= dd) ? ts[t - dd] : 0;
        __syncthreads();
        ts[t] += v;
        __syncthreads();
    }
    int run = ts[t] - s;   // exclusive prefix of this thread's chunk
    for (int i = b; i < e; i++) {
        int v = hrow[i];
        hrow[i] = run;     // in-place exclusive within-digit prefix
        run += v;
    }
    if (t == 255) dtot[d] = ts[255];
}

// ---- scanB: exclusive scan of 256 digit totals -> dbase[0..256]
__global__ __launch_bounds__(256) void scanB_kernel(
    const int* __restrict__ dtot, int* __restrict__ dbase, int E)
{
    __shared__ int ts[256];
    int t = threadIdx.x;
    int s = dtot[t];
    ts[t] = s;
    __syncthreads();
    for (int dd = 1; dd < 256; dd <<= 1) {
        int v = (t >= dd) ? ts[t - dd] : 0;
        __syncthreads();
        ts[t] += v;
        __syncthreads();
    }
    dbase[t] = ts[t] - s;
    if (t == 255) dbase[256] = E;
}

// -------------------- pass1 scatter: bucket by col>>8 (unstable, LDS cursors)
__global__ __launch_bounds__(256) void scatter1_kernel(
    const int* __restrict__ row, const int* __restrict__ col,
    const float* __restrict__ ew, const int* __restrict__ hscan,
    const int* __restrict__ dbase,
    int* __restrict__ keyS, int* __restrict__ srcS, float* __restrict__ ewS,
    int E, int ntiles)
{
    __shared__ int cur[256];
    int t = threadIdx.x;
    int tile = blockIdx.x;
    cur[t] = dbase[t] + hscan[t * ntiles + tile];
    __syncthreads();
    int base = tile * TILE;
    int end = base + TILE; if (end > E) end = E;
    for (int i = base + t; i < end; i += 256) {
        int c = col[i];
        int p = atomicAdd(&cur[c >> 8], 1);
        keyS[p] = c;
        srcS[p] = row[i];
        ewS[p] = ew[i];
    }
}

// ---- pass2: per-bucket counting sort by col&255 + offs + deg/dinv (fused)
__global__ __launch_bounds__(512) void bucket_sort_kernel(
    const int* __restrict__ keyS, const int* __restrict__ srcS,
    const float* __restrict__ ewS, const int* __restrict__ dbase,
    int* __restrict__ srcF, float* __restrict__ wgtF,
    int* __restrict__ offs, float* __restrict__ dinv,
    int E, int N)
{
    __shared__ int   cnt[256];
    __shared__ int   scan[256];
    __shared__ int   cursor[256];
    __shared__ float dsum[256];
    __shared__ float sdinv[256];
    int t = threadIdx.x;
    int b = blockIdx.x;
    if (t == 0 && b == 0) offs[N] = E;
    int bstart = dbase[b];
    int bend   = dbase[b + 1];
    if (t < 256) { cnt[t] = 0; dsum[t] = 0.0f; sdinv[t] = 0.0f; }
    __syncthreads();
    for (int i = bstart + t; i < bend; i += 512) {
        int lo = keyS[i] & 255;
        atomicAdd(&cnt[lo], 1);
        atomicAdd(&dsum[lo], ewS[i]);
    }
    __syncthreads();
    if (t < 256) scan[t] = cnt[t];
    __syncthreads();
    for (int d = 1; d < 256; d <<= 1) {
        int v = 0;
        if (t < 256 && t >= d) v = scan[t - d];
        __syncthreads();
        if (t < 256) scan[t] += v;
        __syncthreads();
    }
    if (t < 256) {
        int excl = scan[t] - cnt[t];
        int c = (b << 8) + t;
        cursor[t] = bstart + excl;
        if (c < N) {
            offs[c] = bstart + excl;
            float deg = 1.0f + dsum[t];
            float di = rsqrtf(deg);
            sdinv[t] = di;
            dinv[c] = di;
        }
    }
    __syncthreads();
    for (int i = bstart + t; i < bend; i += 512) {
        int k = keyS[i];
        int lo = k & 255;
        int p = atomicAdd(&cursor[lo], 1);
        srcF[p] = srcS[i];
        wgtF[p] = ewS[i] * sdinv[lo];   // * dinv[col]; dinv[src] folded into h'
    }
}

// ------------------- GEMM1: h1' = (x @ Wg1) * dinv[row] -> bf16  (128->128)
#define G1_ROWS 64
#define XPAD 68
__global__ __launch_bounds__(256, 4) void gemm1_kernel(
    const float* __restrict__ x, const float* __restrict__ W,
    const float* __restrict__ dinv, unsigned short* __restrict__ h1b, int N)
{
    __shared__ float sx[NF * XPAD];        // sx[k*XPAD + r]
    int t = threadIdx.x;
    int row0 = blockIdx.x * G1_ROWS;
    for (int i = t; i < G1_ROWS * NF; i += 256) {
        int r = i >> 7, k = i & 127;
        int gr = row0 + r;
        sx[k * XPAD + r] = (gr < N) ? x[(size_t)gr * NF + k] : 0.0f;
    }
    __syncthreads();

    int fg = t & 31, rg = t >> 5;
    int f0 = fg * 4, r0 = rg * 8;
    float acc[8][4];
    #pragma unroll
    for (int r = 0; r < 8; r++)
        #pragma unroll
        for (int c = 0; c < 4; c++) acc[r][c] = 0.0f;

    #pragma unroll 8
    for (int k = 0; k < NF; k++) {
        float4 w  = *(const float4*)&W[(size_t)k * NF + f0];
        float4 xa = *(const float4*)&sx[k * XPAD + r0];
        float4 xb = *(const float4*)&sx[k * XPAD + r0 + 4];
        float xr[8] = {xa.x, xa.y, xa.z, xa.w, xb.x, xb.y, xb.z, xb.w};
        #pragma unroll
        for (int r = 0; r < 8; r++) {
            acc[r][0] += xr[r] * w.x;
            acc[r][1] += xr[r] * w.y;
            acc[r][2] += xr[r] * w.z;
            acc[r][3] += xr[r] * w.w;
        }
    }
    #pragma unroll
    for (int r = 0; r < 8; r++) {
        int gr = row0 + r0 + r;
        if (gr < N) {
            float di = dinv[gr];
            uint2 p;
            p.x = pack_bf16x2(acc[r][0] * di, acc[r][1] * di);
            p.y = pack_bf16x2(acc[r][2] * di, acc[r][3] * di);
            *(uint2*)(h1b + (size_t)gr * NF + f0) = p;
        }
    }
}

// --------------- gather1: out1[c] = bg1 + h1'[c]*di + sum_e w*h1'[src]
// one wave per node; 64 lanes x (2xbf16); inner loop unrolled x8 for MLP
__global__ __launch_bounds__(256) void gather1_kernel(
    const int* __restrict__ offs, const int* __restrict__ src,
    const float* __restrict__ wgt, const unsigned short* __restrict__ h1b,
    const float* __restrict__ dinv, const float* __restrict__ bg1,
    float* __restrict__ out1, int N)
{
    int wid  = threadIdx.x >> 6;
    int lane = threadIdx.x & 63;
    int c = blockIdx.x * 4 + wid;
    if (c >= N) return;
    float di = dinv[c];
    unsigned hu = *(const unsigned*)(h1b + (size_t)c * NF + 2 * lane);
    float2 acc;
    acc.x = bg1[2 * lane]     + bf16_lo(hu) * di;  // h1' already has one dinv
    acc.y = bg1[2 * lane + 1] + bf16_hi(hu) * di;

    int beg = offs[c], end = offs[c + 1];
    for (int e0 = beg; e0 < end; e0 += 64) {
        int idx = e0 + lane;
        int   sv = 0; float wv = 0.0f;
        if (idx < end) { sv = src[idx]; wv = wgt[idx]; }
        int m = end - e0; if (m > 64) m = 64;
        int j = 0;
        for (; j + 8 <= m; j += 8) {
            unsigned v[8]; float w[8];
            #pragma unroll
            for (int u = 0; u < 8; u++) {
                int s = __shfl(sv, j + u);
                w[u] = __shfl(wv, j + u);
                v[u] = *(const unsigned*)(h1b + (size_t)s * NF + 2 * lane);
            }
            #pragma unroll
            for (int u = 0; u < 8; u++) {
                acc.x += w[u] * bf16_lo(v[u]);
                acc.y += w[u] * bf16_hi(v[u]);
            }
        }
        for (; j < m; j++) {
            int   s = __shfl(sv, j);
            float w = __shfl(wv, j);
            unsigned v = *(const unsigned*)(h1b + (size_t)s * NF + 2 * lane);
            acc.x += w * bf16_lo(v);
            acc.y += w * bf16_hi(v);
        }
    }
    *(float2*)(out1 + (size_t)c * NF + 2 * lane) = acc;
}

// ----------------- GEMM2: h2' = (relu(out1) @ Wg2) * dinv[row] -> bf16
#define G2_ROWS 64
__global__ __launch_bounds__(256, 4) void gemm2_kernel(
    const float* __restrict__ out1, const float* __restrict__ W,
    const float* __restrict__ dinv, unsigned short* __restrict__ h2b, int N)
{
    __shared__ float sx[NF * XPAD];
    int t = threadIdx.x;
    int row0 = blockIdx.x * G2_ROWS;
    for (int i = t; i < G2_ROWS * NF; i += 256) {
        int r = i >> 7, k = i & 127;
        int gr = row0 + r;
        sx[k * XPAD + r] = (gr < N) ? fmaxf(out1[(size_t)gr * NF + k], 0.0f) : 0.0f;
    }
    __syncthreads();

    int fg = t & 15, rg = t >> 4;
    int f0 = fg * 4;
    int f0c = (f0 <= NCLS - 4) ? f0 : (NCLS - 4);
    int r0 = rg * 4;
    float acc[4][4];
    #pragma unroll
    for (int r = 0; r < 4; r++)
        #pragma unroll
        for (int c = 0; c < 4; c++) acc[r][c] = 0.0f;

    #pragma unroll 8
    for (int k = 0; k < NF; k++) {
        float4 w  = *(const float4*)&W[(size_t)k * NCLS + f0c];
        float4 xa = *(const float4*)&sx[k * XPAD + r0];
        float xr[4] = {xa.x, xa.y, xa.z, xa.w};
        #pragma unroll
        for (int r = 0; r < 4; r++) {
            acc[r][0] += xr[r] * w.x;
            acc[r][1] += xr[r] * w.y;
            acc[r][2] += xr[r] * w.z;
            acc[r][3] += xr[r] * w.w;
        }
    }
    if (f0 <= NCLS - 4) {
        #pragma unroll
        for (int r = 0; r < 4; r++) {
            int gr = row0 + r0 + r;
            if (gr < N) {
                float di = dinv[gr];
                uint2 p;
                p.x = pack_bf16x2(acc[r][0] * di, acc[r][1] * di);
                p.y = pack_bf16x2(acc[r][2] * di, acc[r][3] * di);
                *(uint2*)(h2b + (size_t)gr * NCLS + f0) = p;
            }
        }
    }
}

// --------------- gather2: out[c] = bg2 + h2'[c]*di + sum_e w*h2'[src]
// lanes 0..19 each handle 2 feats (2xbf16 per load)
__global__ __launch_bounds__(256) void gather2_kernel(
    const int* __restrict__ offs, const int* __restrict__ src,
    const float* __restrict__ wgt, const unsigned short* __restrict__ h2b,
    const float* __restrict__ dinv, const float* __restrict__ bg2,
    float* __restrict__ out, int N)
{
    int wid  = threadIdx.x >> 6;
    int lane = threadIdx.x & 63;
    int c = blockIdx.x * 4 + wid;
    if (c >= N) return;
    float di = dinv[c];
    float2 acc = {0.0f, 0.0f};
    if (lane < NCLS / 2) {
        unsigned hu = *(const unsigned*)(h2b + (size_t)c * NCLS + 2 * lane);
        acc.x = bg2[2 * lane]     + bf16_lo(hu) * di;
        acc.y = bg2[2 * lane + 1] + bf16_hi(hu) * di;
    }

    int beg = offs[c], end = offs[c + 1];
    for (int e0 = beg; e0 < end; e0 += 64) {
        int idx = e0 + lane;
        int   sv = 0; float wv = 0.0f;
        if (idx < end) { sv = src[idx]; wv = wgt[idx]; }
        int m = end - e0; if (m > 64) m = 64;
        int j = 0;
        for (; j + 8 <= m; j += 8) {
            unsigned v[8]; float w[8];
            #pragma unroll
            for (int u = 0; u < 8; u++) {
                int s = __shfl(sv, j + u);
                w[u] = __shfl(wv, j + u);
                v[u] = (lane < NCLS / 2)
                     ? *(const unsigned*)(h2b + (size_t)s * NCLS + 2 * lane) : 0u;
            }
            #pragma unroll
            for (int u = 0; u < 8; u++) {
                acc.x += w[u] * bf16_lo(v[u]);
                acc.y += w[u] * bf16_hi(v[u]);
            }
        }
        for (; j < m; j++) {
            int   s = __shfl(sv, j);
            float w = __shfl(wv, j);
            if (lane < NCLS / 2) {
                unsigned v = *(const unsigned*)(h2b + (size_t)s * NCLS + 2 * lane);
                acc.x += w * bf16_lo(v);
                acc.y += w * bf16_hi(v);
            }
        }
    }
    if (lane < NCLS / 2) *(float2*)(out + (size_t)c * NCLS + 2 * lane) = acc;
}

// ============================================================== launch
extern "C" void kernel_launch(void* const* d_in, const int* in_sizes, int n_in,
                              void* d_out, int out_size, void* d_ws, size_t ws_size,
                              hipStream_t stream)
{
    const float* x   = (const float*)d_in[0];
    const int*   ei  = (const int*)d_in[1];
    const float* exf = (const float*)d_in[2];
    const float* W1  = (const float*)d_in[3];
    const float* b1  = (const float*)d_in[4];
    const float* W2  = (const float*)d_in[5];
    const float* b2  = (const float*)d_in[6];
    const float* Wg1 = (const float*)d_in[7];
    const float* bg1 = (const float*)d_in[8];
    const float* Wg2 = (const float*)d_in[9];
    const float* bg2 = (const float*)d_in[10];
    float* out = (float*)d_out;

    int N = in_sizes[0] / NF;
    int E = in_sizes[2] / EF;
    const int* row = ei;
    const int* col = ei + E;
    int ntiles = (E + TILE - 1) / TILE;
    int L = 256 * ntiles;

    // workspace bump allocator (4-byte words)
    char* base = (char*)d_ws;
    size_t off = 0;
    auto alloc = [&](size_t words) -> void* {
        void* p = base + off * 4;
        off += (words + 3) & ~(size_t)3;
        return p;
    };
    // region A: ew + pass1 output (4E words) -- later reused as h1b / h2b
    size_t awords = (size_t)4 * E;
    size_t hwords = ((size_t)N * NF + 1) / 2;   // bf16 h1 = N*128*2B
    if (hwords > awords) awords = hwords;
    float* regA = (float*)alloc(awords);
    float* ew   = regA;
    int*   keyS = (int*)(regA + E);
    int*   srcS = (int*)(regA + 2 * (size_t)E);
    float* ewS  = regA + 3 * (size_t)E;
    unsigned short* h1b = (unsigned short*)regA;  // alias (after sort consumed)
    unsigned short* h2b = (unsigned short*)regA;  // alias (after gather1 consumed)
    // region B: final CSR
    int*   srcF = (int*)  alloc(E);
    float* wgtF = (float*)alloc(E);
    // region C: out1
    float* out1 = (float*)alloc((size_t)N * NF);
    // region D: small
    float* dinv = (float*)alloc(N);
    int*   offs = (int*)  alloc(N + 1);
    int*   hist = (int*)  alloc(L);
    int*   dtot = (int*)  alloc(256);
    int*   dbase= (int*)  alloc(257);

    int nb;
    nb = (E + 255) / 256;
    edge_mlp_kernel<<<nb, 256, 0, stream>>>(exf, W1, b1, W2, b2, ew, E);

    hist1_kernel<<<ntiles, 256, 0, stream>>>(col, hist, E, ntiles);
    scanA_kernel<<<256, 256, 0, stream>>>(hist, dtot, ntiles);
    scanB_kernel<<<1, 256, 0, stream>>>(dtot, dbase, E);
    scatter1_kernel<<<ntiles, 256, 0, stream>>>(row, col, ew, hist, dbase,
                                                keyS, srcS, ewS, E, ntiles);
    bucket_sort_kernel<<<256, 512, 0, stream>>>(keyS, srcS, ewS, dbase,
                                                srcF, wgtF, offs, dinv, E, N);

    nb = (N + G1_ROWS - 1) / G1_ROWS;
    gemm1_kernel<<<nb, 256, 0, stream>>>(x, Wg1, dinv, h1b, N);

    nb = (N + 3) / 4;
    gather1_kernel<<<nb, 256, 0, stream>>>(offs, srcF, wgtF, h1b, dinv, bg1, out1, N);

    nb = (N + G2_ROWS - 1) / G2_ROWS;
    gemm2_kernel<<<nb, 256, 0, stream>>>(out1, Wg2, dinv, h2b, N);

    nb = (N + 3) / 4;
    gather2_kernel<<<nb, 256, 0, stream>>>(offs, srcF, wgtF, h2b, dinv, bg2, out, N);
}

// Round 8
// 432.576 us; speedup vs baseline: 7.6999x; 1.0999x over previous
//
#include <hip/hip_runtime.h>
#include <hip/hip_bf16.h>
#include <math.h>

//  x:        [N,128] f32      (in 0)
//  edge_index[2,E]   i32      (in 1)
//  edge_x:   [E,16]  f32      (in 2)
//  W1 [16,32] b1[32] W2[32,1] b2[1]   (in 3..6)
//  Wg1[128,128] bg1[128] Wg2[128,40] bg2[40]  (in 7..10)
//  out:      [N,40]  f32

#define NF   128
#define EF   16
#define EFIL 32
#define NCLS 40
#define TILE 4096   // edges per tile for pass-1 sort

// pack two fp32 -> 2xbf16 (RTNE), lo in low half
__device__ inline unsigned pack_bf16x2(float a, float b) {
    unsigned ua = __float_as_uint(a);
    unsigned ub = __float_as_uint(b);
    ua += 0x7FFF + ((ua >> 16) & 1);
    ub += 0x7FFF + ((ub >> 16) & 1);
    return (ua >> 16) | (ub & 0xFFFF0000u);
}
__device__ inline float bf16_lo(unsigned u) { return __uint_as_float(u << 16); }
__device__ inline float bf16_hi(unsigned u) { return __uint_as_float(u & 0xFFFF0000u); }

// -------------------------- edge MLP (pure compute, no atomics)
__global__ __launch_bounds__(256) void edge_mlp_kernel(
    const float* __restrict__ ex, const float* __restrict__ W1,
    const float* __restrict__ b1, const float* __restrict__ W2,
    const float* __restrict__ b2, float* __restrict__ ew, int E)
{
    __shared__ float sW1[EF * EFIL];
    __shared__ float sb1[EFIL];
    __shared__ float sW2[EFIL];
    __shared__ float sb2;
    int t = threadIdx.x;
    for (int i = t; i < EF * EFIL; i += 256) sW1[i] = W1[i];
    if (t < EFIL) { sb1[t] = b1[t]; sW2[t] = W2[t]; }
    if (t == 0) sb2 = b2[0];
    __syncthreads();

    int e = blockIdx.x * 256 + t;
    if (e >= E) return;

    float xv[EF];
    const float4* exv = (const float4*)(ex) + (size_t)e * (EF / 4);
    #pragma unroll
    for (int q = 0; q < EF / 4; q++) {
        float4 v = exv[q];
        xv[q * 4 + 0] = v.x; xv[q * 4 + 1] = v.y;
        xv[q * 4 + 2] = v.z; xv[q * 4 + 3] = v.w;
    }
    float acc = sb2;
    #pragma unroll
    for (int j = 0; j < EFIL; j++) {
        float h = sb1[j];
        #pragma unroll
        for (int k = 0; k < EF; k++) h += xv[k] * sW1[k * EFIL + j];
        acc += fmaxf(h, 0.0f) * sW2[j];
    }
    ew[e] = 1.0f / (1.0f + expf(-acc));
}

// -------------------- pass1 histogram: digit = col>>8, LDS only
__global__ __launch_bounds__(256) void hist1_kernel(
    const int* __restrict__ col, int* __restrict__ hist, int E, int ntiles)
{
    __shared__ int h[256];
    int t = threadIdx.x;
    h[t] = 0;
    __syncthreads();
    int tile = blockIdx.x;
    int base = tile * TILE;
    int end = base + TILE; if (end > E) end = E;
    for (int i = base + t; i < end; i += 256)
        atomicAdd(&h[col[i] >> 8], 1);
    __syncthreads();
    hist[t * ntiles + tile] = h[t];
}

// ---- scanA: one block per digit; exclusive scan of hist[d][0..ntiles) in
//      place (digit-major, coalesced), digit total -> dtot[d]
__global__ __launch_bounds__(256) void scanA_kernel(
    int* __restrict__ hist, int* __restrict__ dtot, int ntiles)
{
    __shared__ int ts[256];
    int d = blockIdx.x;
    int t = threadIdx.x;
    int* hrow = hist + (size_t)d * ntiles;
    int C = (ntiles + 255) >> 8;
    int b = t * C;
    int e = b + C; if (e > ntiles) e = ntiles;
    int s = 0;
    for (int i = b; i < e; i++) s += hrow[i];
    ts[t] = s;
    __syncthreads();
    for (int dd = 1; dd < 256; dd <<= 1) {
        int v = (t >= dd) ? ts[t - dd] : 0;
        __syncthreads();
        ts[t] += v;
        __syncthreads();
    }
    int run = ts[t] - s;   // exclusive prefix of this thread's chunk
    for (int i = b; i < e; i++) {
        int v = hrow[i];
        hrow[i] = run;     // in-place exclusive within-digit prefix
        run += v;
    }
    if (t == 255) dtot[d] = ts[255];
}

// ---- scanB: exclusive scan of 256 digit totals -> dbase[0..256]
__global__ __launch_bounds__(256) void scanB_kernel(
    const int* __restrict__ dtot, int* __restrict__ dbase, int E)
{
    __shared__ int ts[256];
    int t = threadIdx.x;
    int s = dtot[t];
    ts[t] = s;
    __syncthreads();
    for (int dd = 1; dd < 256; dd <<= 1) {
        int v = (t >= dd) ? ts[t - dd] : 0;
        __syncthreads();
        ts[t] += v;
        __syncthreads();
    }
    dbase[t] = ts[t] - s;
    if (t == 255) dbase[256] = E;
}

// ---- pass1 scatter: bucket by col>>8; ONE 16B store per edge (packed record)
__global__ __launch_bounds__(512) void scatter1_kernel(
    const int* __restrict__ row, const int* __restrict__ col,
    const float* __restrict__ ew, const int* __restrict__ hscan,
    const int* __restrict__ dbase,
    uint4* __restrict__ st, int E, int ntiles)
{
    __shared__ int cur[256];
    int t = threadIdx.x;
    int tile = blockIdx.x;
    if (t < 256) cur[t] = dbase[t] + hscan[t * ntiles + tile];
    __syncthreads();
    int base = tile * TILE;
    int end = base + TILE; if (end > E) end = E;
    for (int i = base + t; i < end; i += 512) {
        int c = col[i];
        int r = row[i];
        float w = ew[i];
        int p = atomicAdd(&cur[c >> 8], 1);
        st[p] = make_uint4((unsigned)c, (unsigned)r, __float_as_uint(w), 0u);
    }
}

// ---- pass2: per-bucket counting sort by col&255 + offs + deg/dinv (fused)
//      reads packed 16B records, writes packed 8B final records
__global__ __launch_bounds__(512) void bucket_sort_kernel(
    const uint4* __restrict__ st, const int* __restrict__ dbase,
    uint2* __restrict__ edgeF, int* __restrict__ offs, float* __restrict__ dinv,
    int E, int N)
{
    __shared__ int   cnt[256];
    __shared__ int   scan[256];
    __shared__ int   cursor[256];
    __shared__ float dsum[256];
    __shared__ float sdinv[256];
    int t = threadIdx.x;
    int b = blockIdx.x;
    if (t == 0 && b == 0) offs[N] = E;
    int bstart = dbase[b];
    int bend   = dbase[b + 1];
    if (t < 256) { cnt[t] = 0; dsum[t] = 0.0f; sdinv[t] = 0.0f; }
    __syncthreads();
    for (int i = bstart + t; i < bend; i += 512) {
        uint4 v = st[i];
        int lo = (int)(v.x & 255u);
        atomicAdd(&cnt[lo], 1);
        atomicAdd(&dsum[lo], __uint_as_float(v.z));
    }
    __syncthreads();
    if (t < 256) scan[t] = cnt[t];
    __syncthreads();
    for (int d = 1; d < 256; d <<= 1) {
        int v = 0;
        if (t < 256 && t >= d) v = scan[t - d];
        __syncthreads();
        if (t < 256) scan[t] += v;
        __syncthreads();
    }
    if (t < 256) {
        int excl = scan[t] - cnt[t];
        int c = (b << 8) + t;
        cursor[t] = bstart + excl;
        if (c < N) {
            offs[c] = bstart + excl;
            float deg = 1.0f + dsum[t];
            float di = rsqrtf(deg);
            sdinv[t] = di;
            dinv[c] = di;
        }
    }
    __syncthreads();
    for (int i = bstart + t; i < bend; i += 512) {
        uint4 v = st[i];
        int lo = (int)(v.x & 255u);
        int p = atomicAdd(&cursor[lo], 1);
        float w = __uint_as_float(v.z) * sdinv[lo];  // * dinv[col]; dinv[src] in h'
        edgeF[p] = make_uint2(v.y, __float_as_uint(w));
    }
}

// ------------------- GEMM1: h1' = (x @ Wg1) * dinv[row] -> bf16  (128->128)
#define G1_ROWS 64
#define XPAD 68
__global__ __launch_bounds__(256, 4) void gemm1_kernel(
    const float* __restrict__ x, const float* __restrict__ W,
    const float* __restrict__ dinv, unsigned short* __restrict__ h1b, int N)
{
    __shared__ float sx[NF * XPAD];        // sx[k*XPAD + r]
    int t = threadIdx.x;
    int row0 = blockIdx.x * G1_ROWS;
    for (int i = t; i < G1_ROWS * NF; i += 256) {
        int r = i >> 7, k = i & 127;
        int gr = row0 + r;
        sx[k * XPAD + r] = (gr < N) ? x[(size_t)gr * NF + k] : 0.0f;
    }
    __syncthreads();

    int fg = t & 31, rg = t >> 5;
    int f0 = fg * 4, r0 = rg * 8;
    float acc[8][4];
    #pragma unroll
    for (int r = 0; r < 8; r++)
        #pragma unroll
        for (int c = 0; c < 4; c++) acc[r][c] = 0.0f;

    #pragma unroll 8
    for (int k = 0; k < NF; k++) {
        float4 w  = *(const float4*)&W[(size_t)k * NF + f0];
        float4 xa = *(const float4*)&sx[k * XPAD + r0];
        float4 xb = *(const float4*)&sx[k * XPAD + r0 + 4];
        float xr[8] = {xa.x, xa.y, xa.z, xa.w, xb.x, xb.y, xb.z, xb.w};
        #pragma unroll
        for (int r = 0; r < 8; r++) {
            acc[r][0] += xr[r] * w.x;
            acc[r][1] += xr[r] * w.y;
            acc[r][2] += xr[r] * w.z;
            acc[r][3] += xr[r] * w.w;
        }
    }
    #pragma unroll
    for (int r = 0; r < 8; r++) {
        int gr = row0 + r0 + r;
        if (gr < N) {
            float di = dinv[gr];
            uint2 p;
            p.x = pack_bf16x2(acc[r][0] * di, acc[r][1] * di);
            p.y = pack_bf16x2(acc[r][2] * di, acc[r][3] * di);
            *(uint2*)(h1b + (size_t)gr * NF + f0) = p;
        }
    }
}

// --------------- gather1: out1[c] = bg1 + h1'[c]*di + sum_e w*h1'[src]
// one wave per node; 64 lanes x (2xbf16); inner loop unrolled x8 for MLP
__global__ __launch_bounds__(256) void gather1_kernel(
    const int* __restrict__ offs, const uint2* __restrict__ edgeF,
    const unsigned short* __restrict__ h1b,
    const float* __restrict__ dinv, const float* __restrict__ bg1,
    float* __restrict__ out1, int N)
{
    int wid  = threadIdx.x >> 6;
    int lane = threadIdx.x & 63;
    int c = blockIdx.x * 4 + wid;
    if (c >= N) return;
    float di = dinv[c];
    unsigned hu = *(const unsigned*)(h1b + (size_t)c * NF + 2 * lane);
    float2 acc;
    acc.x = bg1[2 * lane]     + bf16_lo(hu) * di;  // h1' already has one dinv
    acc.y = bg1[2 * lane + 1] + bf16_hi(hu) * di;

    int beg = offs[c], end = offs[c + 1];
    for (int e0 = beg; e0 < end; e0 += 64) {
        int idx = e0 + lane;
        uint2 eg = make_uint2(0u, 0u);
        if (idx < end) eg = edgeF[idx];
        int sv = (int)eg.x; float wv = __uint_as_float(eg.y);
        int m = end - e0; if (m > 64) m = 64;
        int j = 0;
        for (; j + 8 <= m; j += 8) {
            unsigned v[8]; float w[8];
            #pragma unroll
            for (int u = 0; u < 8; u++) {
                int s = __shfl(sv, j + u);
                w[u] = __shfl(wv, j + u);
                v[u] = *(const unsigned*)(h1b + (size_t)s * NF + 2 * lane);
            }
            #pragma unroll
            for (int u = 0; u < 8; u++) {
                acc.x += w[u] * bf16_lo(v[u]);
                acc.y += w[u] * bf16_hi(v[u]);
            }
        }
        for (; j < m; j++) {
            int   s = __shfl(sv, j);
            float w = __shfl(wv, j);
            unsigned v = *(const unsigned*)(h1b + (size_t)s * NF + 2 * lane);
            acc.x += w * bf16_lo(v);
            acc.y += w * bf16_hi(v);
        }
    }
    *(float2*)(out1 + (size_t)c * NF + 2 * lane) = acc;
}

// ----------------- GEMM2: h2' = (relu(out1) @ Wg2) * dinv[row] -> bf16
#define G2_ROWS 64
__global__ __launch_bounds__(256, 4) void gemm2_kernel(
    const float* __restrict__ out1, const float* __restrict__ W,
    const float* __restrict__ dinv, unsigned short* __restrict__ h2b, int N)
{
    __shared__ float sx[NF * XPAD];
    int t = threadIdx.x;
    int row0 = blockIdx.x * G2_ROWS;
    for (int i = t; i < G2_ROWS * NF; i += 256) {
        int r = i >> 7, k = i & 127;
        int gr = row0 + r;
        sx[k * XPAD + r] = (gr < N) ? fmaxf(out1[(size_t)gr * NF + k], 0.0f) : 0.0f;
    }
    __syncthreads();

    int fg = t & 15, rg = t >> 4;
    int f0 = fg * 4;
    int f0c = (f0 <= NCLS - 4) ? f0 : (NCLS - 4);
    int r0 = rg * 4;
    float acc[4][4];
    #pragma unroll
    for (int r = 0; r < 4; r++)
        #pragma unroll
        for (int c = 0; c < 4; c++) acc[r][c] = 0.0f;

    #pragma unroll 8
    for (int k = 0; k < NF; k++) {
        float4 w  = *(const float4*)&W[(size_t)k * NCLS + f0c];
        float4 xa = *(const float4*)&sx[k * XPAD + r0];
        float xr[4] = {xa.x, xa.y, xa.z, xa.w};
        #pragma unroll
        for (int r = 0; r < 4; r++) {
            acc[r][0] += xr[r] * w.x;
            acc[r][1] += xr[r] * w.y;
            acc[r][2] += xr[r] * w.z;
            acc[r][3] += xr[r] * w.w;
        }
    }
    if (f0 <= NCLS - 4) {
        #pragma unroll
        for (int r = 0; r < 4; r++) {
            int gr = row0 + r0 + r;
            if (gr < N) {
                float di = dinv[gr];
                uint2 p;
                p.x = pack_bf16x2(acc[r][0] * di, acc[r][1] * di);
                p.y = pack_bf16x2(acc[r][2] * di, acc[r][3] * di);
                *(uint2*)(h2b + (size_t)gr * NCLS + f0) = p;
            }
        }
    }
}

// --------------- gather2: out[c] = bg2 + h2'[c]*di + sum_e w*h2'[src]
// lanes 0..19 each handle 2 feats (2xbf16 per load)
__global__ __launch_bounds__(256) void gather2_kernel(
    const int* __restrict__ offs, const uint2* __restrict__ edgeF,
    const unsigned short* __restrict__ h2b,
    const float* __restrict__ dinv, const float* __restrict__ bg2,
    float* __restrict__ out, int N)
{
    int wid  = threadIdx.x >> 6;
    int lane = threadIdx.x & 63;
    int c = blockIdx.x * 4 + wid;
    if (c >= N) return;
    float di = dinv[c];
    float2 acc = {0.0f, 0.0f};
    if (lane < NCLS / 2) {
        unsigned hu = *(const unsigned*)(h2b + (size_t)c * NCLS + 2 * lane);
        acc.x = bg2[2 * lane]     + bf16_lo(hu) * di;
        acc.y = bg2[2 * lane + 1] + bf16_hi(hu) * di;
    }

    int beg = offs[c], end = offs[c + 1];
    for (int e0 = beg; e0 < end; e0 += 64) {
        int idx = e0 + lane;
        uint2 eg = make_uint2(0u, 0u);
        if (idx < end) eg = edgeF[idx];
        int sv = (int)eg.x; float wv = __uint_as_float(eg.y);
        int m = end - e0; if (m > 64) m = 64;
        int j = 0;
        for (; j + 8 <= m; j += 8) {
            unsigned v[8]; float w[8];
            #pragma unroll
            for (int u = 0; u < 8; u++) {
                int s = __shfl(sv, j + u);
                w[u] = __shfl(wv, j + u);
                v[u] = (lane < NCLS / 2)
                     ? *(const unsigned*)(h2b + (size_t)s * NCLS + 2 * lane) : 0u;
            }
            #pragma unroll
            for (int u = 0; u < 8; u++) {
                acc.x += w[u] * bf16_lo(v[u]);
                acc.y += w[u] * bf16_hi(v[u]);
            }
        }
        for (; j < m; j++) {
            int   s = __shfl(sv, j);
            float w = __shfl(wv, j);
            if (lane < NCLS / 2) {
                unsigned v = *(const unsigned*)(h2b + (size_t)s * NCLS + 2 * lane);
                acc.x += w * bf16_lo(v);
                acc.y += w * bf16_hi(v);
            }
        }
    }
    if (lane < NCLS / 2) *(float2*)(out + (size_t)c * NCLS + 2 * lane) = acc;
}

// ============================================================== launch
extern "C" void kernel_launch(void* const* d_in, const int* in_sizes, int n_in,
                              void* d_out, int out_size, void* d_ws, size_t ws_size,
                              hipStream_t stream)
{
    const float* x   = (const float*)d_in[0];
    const int*   ei  = (const int*)d_in[1];
    const float* exf = (const float*)d_in[2];
    const float* W1  = (const float*)d_in[3];
    const float* b1  = (const float*)d_in[4];
    const float* W2  = (const float*)d_in[5];
    const float* b2  = (const float*)d_in[6];
    const float* Wg1 = (const float*)d_in[7];
    const float* bg1 = (const float*)d_in[8];
    const float* Wg2 = (const float*)d_in[9];
    const float* bg2 = (const float*)d_in[10];
    float* out = (float*)d_out;

    int N = in_sizes[0] / NF;
    int E = in_sizes[2] / EF;
    const int* row = ei;
    const int* col = ei + E;
    int ntiles = (E + TILE - 1) / TILE;
    int L = 256 * ntiles;

    // workspace bump allocator (4-byte words)
    char* base = (char*)d_ws;
    size_t off = 0;
    auto alloc = [&](size_t words) -> void* {
        void* p = base + off * 4;
        off += (words + 3) & ~(size_t)3;
        return p;
    };
    // region A: ew (E words) + staged uint4 records (4E words); h1b/h2b alias
    float* ew   = (float*)alloc(E);
    size_t stwords = (size_t)4 * E;
    size_t hwords = ((size_t)N * NF + 1) / 2;   // bf16 h1 = N*128*2B
    if (hwords > stwords) stwords = hwords;
    uint4* st   = (uint4*)alloc(stwords);
    unsigned short* h1b = (unsigned short*)st;   // alias (after sort consumed)
    unsigned short* h2b = (unsigned short*)st;   // alias (after gather1 consumed)
    // region B: final CSR (packed 8B records)
    uint2* edgeF = (uint2*)alloc((size_t)2 * E);
    // region C: out1
    float* out1 = (float*)alloc((size_t)N * NF);
    // region D: small
    float* dinv = (float*)alloc(N);
    int*   offs = (int*)  alloc(N + 1);
    int*   hist = (int*)  alloc(L);
    int*   dtot = (int*)  alloc(256);
    int*   dbase= (int*)  alloc(257);

    int nb;
    nb = (E + 255) / 256;
    edge_mlp_kernel<<<nb, 256, 0, stream>>>(exf, W1, b1, W2, b2, ew, E);

    hist1_kernel<<<ntiles, 256, 0, stream>>>(col, hist, E, ntiles);
    scanA_kernel<<<256, 256, 0, stream>>>(hist, dtot, ntiles);
    scanB_kernel<<<1, 256, 0, stream>>>(dtot, dbase, E);
    scatter1_kernel<<<ntiles, 512, 0, stream>>>(row, col, ew, hist, dbase,
                                                st, E, ntiles);
    bucket_sort_kernel<<<256, 512, 0, stream>>>(st, dbase, edgeF, offs, dinv, E, N);

    nb = (N + G1_ROWS - 1) / G1_ROWS;
    gemm1_kernel<<<nb, 256, 0, stream>>>(x, Wg1, dinv, h1b, N);

    nb = (N + 3) / 4;
    gather1_kernel<<<nb, 256, 0, stream>>>(offs, edgeF, h1b, dinv, bg1, out1, N);

    nb = (N + G2_ROWS - 1) / G2_ROWS;
    gemm2_kernel<<<nb, 256, 0, stream>>>(out1, Wg2, dinv, h2b, N);

    nb = (N + 3) / 4;
    gather2_kernel<<<nb, 256, 0, stream>>>(offs, edgeF, h2b, dinv, bg2, out, N);
}